// Round 20
// baseline (525.284 us; speedup 1.0000x reference)
//
#include <hip/hip_runtime.h>
#include <math.h>

__device__ __forceinline__ void gload16(const float* g, float* l) {
    __builtin_amdgcn_global_load_lds(
        (const __attribute__((address_space(1))) void*)g,
        (__attribute__((address_space(3))) void*)l, 16, 0, 0);
}

// ---------------- stats phase 1 ----------------
__device__ __forceinline__ double wred_add(double v) {
    #pragma unroll
    for (int o = 32; o > 0; o >>= 1) v += __shfl_xor(v, o);
    return v;
}
__device__ __forceinline__ float wred_min(float v) {
    #pragma unroll
    for (int o = 32; o > 0; o >>= 1) v = fminf(v, __shfl_xor(v, o));
    return v;
}
__device__ __forceinline__ float wred_max(float v) {
    #pragma unroll
    for (int o = 32; o > 0; o >>= 1) v = fmaxf(v, __shfl_xor(v, o));
    return v;
}

#define PREC 17

__global__ __launch_bounds__(256) void stats_partial_kernel(const float* __restrict__ img,
                                                            double* __restrict__ part)
{
    int b = blockIdx.x >> 5, blk = blockIdx.x & 31;
    int tid = threadIdx.x;
    const float* r0 = img + (size_t)b * 3 * 65536;
    const float* g0 = r0 + 65536;
    const float* b0 = r0 + 131072;
    int base = blk*2048 + tid*8;
    double s0=0,s1=0,s2=0,q0=0,q1=0,q2=0,l1=0,l2=0,l3=0,l4=0,dark=0;
    float mn0=1e30f,mn1=1e30f,mn2=1e30f, mx0=-1e30f,mx1=-1e30f,mx2=-1e30f;
    #pragma unroll
    for (int u = 0; u < 2; ++u) {
        float4 rv = *(const float4*)&r0[base + u*4];
        float4 gv = *(const float4*)&g0[base + u*4];
        float4 bv = *(const float4*)&b0[base + u*4];
        float rr[4] = {rv.x, rv.y, rv.z, rv.w};
        float gg[4] = {gv.x, gv.y, gv.z, gv.w};
        float bbv[4] = {bv.x, bv.y, bv.z, bv.w};
        #pragma unroll
        for (int e = 0; e < 4; ++e) {
            float r = rr[e], g = gg[e], bl = bbv[e];
            double rd_ = r, gd = g, bd = bl;
            s0 += rd_; q0 += rd_*rd_; mn0 = fminf(mn0, r); mx0 = fmaxf(mx0, r);
            s1 += gd;  q1 += gd*gd;   mn1 = fminf(mn1, g); mx1 = fmaxf(mx1, g);
            s2 += bd;  q2 += bd*bd;   mn2 = fminf(mn2, bl); mx2 = fmaxf(mx2, bl);
            double lum = 0.299*rd_ + 0.587*gd + 0.114*bd;
            double d2 = lum*lum;
            l1 += lum; l2 += d2; l3 += d2*lum; l4 += d2*d2;
            if (lum < 0.2) dark += 1.0;
        }
    }
    double dv[11] = {s0,s1,s2,q0,q1,q2,l1,l2,l3,l4,dark};
    #pragma unroll
    for (int q = 0; q < 11; ++q) dv[q] = wred_add(dv[q]);
    mn0 = wred_min(mn0); mn1 = wred_min(mn1); mn2 = wred_min(mn2);
    mx0 = wred_max(mx0); mx1 = wred_max(mx1); mx2 = wred_max(mx2);
    __shared__ double sd[4][PREC];
    int w = tid >> 6, lane = tid & 63;
    if (lane == 0) {
        #pragma unroll
        for (int q = 0; q < 11; ++q) sd[w][q] = dv[q];
        sd[w][11] = (double)mn0; sd[w][12] = (double)mn1; sd[w][13] = (double)mn2;
        sd[w][14] = (double)mx0; sd[w][15] = (double)mx1; sd[w][16] = (double)mx2;
    }
    __syncthreads();
    if (tid == 0) {
        double out[PREC];
        #pragma unroll
        for (int q = 0; q < PREC; ++q) out[q] = sd[0][q];
        #pragma unroll
        for (int ww = 1; ww < 4; ++ww) {
            #pragma unroll
            for (int q = 0; q < 11; ++q) out[q] += sd[ww][q];
            out[11] = fmin(out[11], sd[ww][11]); out[12] = fmin(out[12], sd[ww][12]);
            out[13] = fmin(out[13], sd[ww][13]);
            out[14] = fmax(out[14], sd[ww][14]); out[15] = fmax(out[15], sd[ww][15]);
            out[16] = fmax(out[16], sd[ww][16]);
        }
        double* p = part + (size_t)(b*32 + blk)*PREC;
        #pragma unroll
        for (int q = 0; q < PREC; ++q) p[q] = out[q];
    }
}

// ---------------- stats phase 2 ----------------
__global__ __launch_bounds__(32) void stats_final_kernel(const double* __restrict__ part,
                                                         double* __restrict__ feats)
{
    int b = blockIdx.x, t = threadIdx.x;
    const double* p = part + (size_t)(b*32 + t)*PREC;
    double v[PREC];
    #pragma unroll
    for (int q = 0; q < PREC; ++q) v[q] = p[q];
    #pragma unroll
    for (int o = 16; o > 0; o >>= 1) {
        #pragma unroll
        for (int q = 0; q < 11; ++q) v[q] += __shfl_xor(v[q], o);
        #pragma unroll
        for (int q = 11; q < 14; ++q) v[q] = fmin(v[q], __shfl_xor(v[q], o));
        #pragma unroll
        for (int q = 14; q < PREC; ++q) v[q] = fmax(v[q], __shfl_xor(v[q], o));
    }
    if (t == 0) {
        const double n = 65536.0;
        double* f = feats + b*15;
        for (int c = 0; c < 3; ++c) {
            double su = v[c], sq = v[3+c];
            f[c]   = su/n;
            f[3+c] = sqrt((sq - su*su/n) / (n - 1.0));
            f[6+c] = v[11+c];
            f[9+c] = v[14+c];
        }
        double m1 = v[6]/n, m2 = v[7]/n, m3 = v[8]/n, m4 = v[9]/n;
        double mu2 = m2 - m1*m1;
        double mu3 = m3 - 3.0*m1*m2 + 2.0*m1*m1*m1;
        double mu4 = m4 - 4.0*m1*m3 + 6.0*m1*m1*m2 - 3.0*m1*m1*m1*m1;
        double sd = sqrt(mu2);
        f[12] = mu3 / (sd*sd*sd + 1e-6);
        f[13] = mu4 / (sd*sd*sd*sd + 1e-6);
        f[14] = v[10] / n;
    }
}

// ---------------- stat MLP ----------------
__global__ __launch_bounds__(128) void sfmlp_kernel(const double* __restrict__ feats,
    const float* __restrict__ w1, const float* __restrict__ b1,
    const float* __restrict__ w2, const float* __restrict__ b2,
    double* __restrict__ sf)
{
    int b = blockIdx.x, t = threadIdx.x;
    __shared__ double fs[15];
    __shared__ double hs[128];
    if (t < 15) fs[t] = feats[b*15 + t];
    __syncthreads();
    double h = (double)b1[t];
    for (int j = 0; j < 15; ++j) h += fs[j] * (double)w1[t*15 + j];
    hs[t] = fmax(h, 0.0);
    __syncthreads();
    double o = (double)b2[t];
    for (int j = 0; j < 128; ++j) o += hs[j] * (double)w2[t*128 + j];
    sf[b*128 + t] = o;
}

__device__ __forceinline__ int swz64(int r, int kq4) {
    return r*64 + (((kq4) ^ (r & 15)) << 2);
}

// ---------------- patch embedding split-K x4 gather-GEMM ----------------
__global__ __launch_bounds__(256) void patch_sk_kernel(const float* __restrict__ img,
    const float* __restrict__ w, float* __restrict__ Pa, float* __restrict__ Pb4)
{
    __shared__ float As[4096];
    __shared__ float Ws[4096];
    int tid = threadIdx.x;
    int tx = tid & 15, ty = tid >> 4;
    int m0 = blockIdx.x * 64, n0 = blockIdx.y * 64;
    int z = blockIdx.z;
    int kbase = z * 192;
    int wv = tid >> 6;
    float acc[4][4] = {};
    for (int k0 = 0; k0 < 192; k0 += 64) {
        #pragma unroll
        for (int call = 0; call < 4; ++call) {
            int s = call*256 + tid;
            int row = s >> 4, kq = (s & 15) ^ (row & 15);
            int m = m0 + row;
            int bb = m >> 8, pat = m & 255;
            int gy = pat >> 4, gx = pat & 15;
            int k = kbase + k0 + kq*4;
            int c = k >> 8, rem = k & 255;
            int py = rem >> 4, px = rem & 15;
            gload16(&img[(size_t)(bb*3 + c)*65536 + (size_t)(gy*16+py)*256 + gx*16 + px],
                    As + (call*256 + wv*64)*4);
            gload16(&w[(size_t)(n0+row)*768 + k], Ws + (call*256 + wv*64)*4);
        }
        __syncthreads();
        #pragma unroll 8
        for (int q = 0; q < 16; ++q) {
            float4 a4[4], w4[4];
            #pragma unroll
            for (int i=0;i<4;++i) a4[i] = *(const float4*)&As[swz64(ty + 16*i, q)];
            #pragma unroll
            for (int j=0;j<4;++j) w4[j] = *(const float4*)&Ws[swz64(tx + 16*j, q)];
            #pragma unroll
            for (int i=0;i<4;++i)
                #pragma unroll
                for (int j=0;j<4;++j) {
                    acc[i][j] = fmaf(a4[i].x, w4[j].x, acc[i][j]);
                    acc[i][j] = fmaf(a4[i].y, w4[j].y, acc[i][j]);
                    acc[i][j] = fmaf(a4[i].z, w4[j].z, acc[i][j]);
                    acc[i][j] = fmaf(a4[i].w, w4[j].w, acc[i][j]);
                }
        }
        __syncthreads();
    }
    float* P = (z < 3) ? (Pa + (size_t)z*2097152) : Pb4;
    #pragma unroll
    for (int i=0;i<4;++i){
        int m = m0 + ty + 16*i;
        #pragma unroll
        for (int j=0;j<4;++j){
            int n = n0 + tx + 16*j;
            P[(size_t)m*128 + n] = acc[i][j];
        }
    }
}

// ---------------- f32 GEMM (global_load_lds staging), epi 0=store+bias, 2=gelu ----------------
__global__ __launch_bounds__(256) void gemm_kernel(const float* __restrict__ A, int lda,
    const float* __restrict__ W, const float* __restrict__ bias,
    float* __restrict__ C, int M, int N, int K, int epi)
{
    __shared__ float As[4096];
    __shared__ float Ws[4096];
    int tid = threadIdx.x;
    int tx = tid & 15, ty = tid >> 4;
    int m0 = blockIdx.x * 64, n0 = blockIdx.y * 64;
    int wv = tid >> 6;
    float acc[4][4] = {};
    for (int k0 = 0; k0 < K; k0 += 64) {
        #pragma unroll
        for (int call = 0; call < 4; ++call) {
            int s = call*256 + tid;
            int row = s >> 4, kq = (s & 15) ^ (row & 15);
            gload16(&A[(size_t)(m0+row)*lda + k0 + kq*4], As + (call*256 + wv*64)*4);
            gload16(&W[(size_t)(n0+row)*K + k0 + kq*4], Ws + (call*256 + wv*64)*4);
        }
        __syncthreads();
        #pragma unroll 8
        for (int q = 0; q < 16; ++q) {
            float4 a4[4], w4[4];
            #pragma unroll
            for (int i=0;i<4;++i) a4[i] = *(const float4*)&As[swz64(ty + 16*i, q)];
            #pragma unroll
            for (int j=0;j<4;++j) w4[j] = *(const float4*)&Ws[swz64(tx + 16*j, q)];
            #pragma unroll
            for (int i=0;i<4;++i)
                #pragma unroll
                for (int j=0;j<4;++j) {
                    acc[i][j] = fmaf(a4[i].x, w4[j].x, acc[i][j]);
                    acc[i][j] = fmaf(a4[i].y, w4[j].y, acc[i][j]);
                    acc[i][j] = fmaf(a4[i].z, w4[j].z, acc[i][j]);
                    acc[i][j] = fmaf(a4[i].w, w4[j].w, acc[i][j]);
                }
        }
        __syncthreads();
    }
    #pragma unroll
    for (int i=0;i<4;++i){
        int m = m0 + ty + 16*i;
        #pragma unroll
        for (int j=0;j<4;++j){
            int n = n0 + tx + 16*j;
            float v = acc[i][j] + bias[n];
            if (epi == 0) {
                C[(size_t)m*N + n] = v;
            } else {
                C[(size_t)m*N + n] = 0.5f*v*(1.0f + erff(v*0.70710678118654752f));
            }
        }
    }
}

// ---------------- split-K f32 GEMM ----------------
__global__ __launch_bounds__(256) void gemm_sk_kernel(const float* __restrict__ A, int lda,
    const float* __restrict__ W, int K, int K2,
    float* __restrict__ P0, float* __restrict__ P1, int ldo)
{
    __shared__ float As[4096];
    __shared__ float Ws[4096];
    int tid = threadIdx.x;
    int tx = tid & 15, ty = tid >> 4;
    int m0 = blockIdx.x * 64, n0 = blockIdx.y * 64;
    int kbase = blockIdx.z * K2;
    int wv = tid >> 6;
    float acc[4][4] = {};
    for (int k0 = 0; k0 < K2; k0 += 64) {
        #pragma unroll
        for (int call = 0; call < 4; ++call) {
            int s = call*256 + tid;
            int row = s >> 4, kq = (s & 15) ^ (row & 15);
            gload16(&A[(size_t)(m0+row)*lda + kbase + k0 + kq*4], As + (call*256 + wv*64)*4);
            gload16(&W[(size_t)(n0+row)*K + kbase + k0 + kq*4], Ws + (call*256 + wv*64)*4);
        }
        __syncthreads();
        #pragma unroll 8
        for (int q = 0; q < 16; ++q) {
            float4 a4[4], w4[4];
            #pragma unroll
            for (int i=0;i<4;++i) a4[i] = *(const float4*)&As[swz64(ty + 16*i, q)];
            #pragma unroll
            for (int j=0;j<4;++j) w4[j] = *(const float4*)&Ws[swz64(tx + 16*j, q)];
            #pragma unroll
            for (int i=0;i<4;++i)
                #pragma unroll
                for (int j=0;j<4;++j) {
                    acc[i][j] = fmaf(a4[i].x, w4[j].x, acc[i][j]);
                    acc[i][j] = fmaf(a4[i].y, w4[j].y, acc[i][j]);
                    acc[i][j] = fmaf(a4[i].z, w4[j].z, acc[i][j]);
                    acc[i][j] = fmaf(a4[i].w, w4[j].w, acc[i][j]);
                }
        }
        __syncthreads();
    }
    float* P = blockIdx.z ? P1 : P0;
    #pragma unroll
    for (int i=0;i<4;++i){
        int m = m0 + ty + 16*i;
        #pragma unroll
        for (int j=0;j<4;++j){
            int n = n0 + tx + 16*j;
            P[(size_t)m*ldo + n] = acc[i][j];
        }
    }
}

// ---------------- combine: x = (((p0+p1)+p2)+p3)+bias+pos+sf ; h = LN(x) ----------------
__global__ __launch_bounds__(256) void cpatch_kernel(const float* __restrict__ pa,
    const float* __restrict__ p3, const float* __restrict__ bias,
    const float* __restrict__ pos, const double* __restrict__ sf,
    const float* __restrict__ ls, const float* __restrict__ lb,
    float* __restrict__ x, float* __restrict__ h)
{
    int tid = threadIdx.x;
    int lane = tid & 63, w = tid >> 6;
    int row = blockIdx.x*4 + w;
    int bb = row >> 8, pat = row & 255;
    int n = lane*2;
    float2 a0 = *(const float2*)&pa[(size_t)row*128 + n];
    float2 a1 = *(const float2*)&pa[2097152 + (size_t)row*128 + n];
    float2 a2 = *(const float2*)&pa[4194304 + (size_t)row*128 + n];
    float2 a3 = *(const float2*)&p3[(size_t)row*128 + n];
    float v0 = ((a0.x + a1.x) + a2.x) + a3.x + bias[n]   + pos[pat*128 + n]   + (float)sf[bb*128 + n];
    float v1 = ((a0.y + a1.y) + a2.y) + a3.y + bias[n+1] + pos[pat*128 + n+1] + (float)sf[bb*128 + n+1];
    *(float2*)&x[(size_t)row*128 + n] = make_float2(v0, v1);
    double v0d = v0, v1d = v1;
    double sum = v0d + v1d, sq = v0d*v0d + v1d*v1d;
    #pragma unroll
    for (int o = 32; o > 0; o >>= 1) { sum += __shfl_xor(sum, o); sq += __shfl_xor(sq, o); }
    double mean = sum * (1.0/128.0);
    double var  = sq  * (1.0/128.0) - mean*mean;
    double inv  = 1.0 / sqrt(var + 1e-5);
    float2 o2;
    o2.x = (float)((v0d - mean)*inv*(double)ls[n]   + (double)lb[n]);
    o2.y = (float)((v1d - mean)*inv*(double)ls[n+1] + (double)lb[n+1]);
    *(float2*)&h[(size_t)row*128 + n] = o2;
}

// ---------------- combine: x += (p0+p1)+bias ; optional h = LN(x) ----------------
__global__ __launch_bounds__(256) void cres_kernel(float* __restrict__ x,
    const float* __restrict__ p0, int ld0, const float* __restrict__ p1, int ld1,
    const float* __restrict__ bias,
    const float* __restrict__ ls, const float* __restrict__ lb,
    float* __restrict__ h, int doLN)
{
    int tid = threadIdx.x;
    int lane = tid & 63, w = tid >> 6;
    int row = blockIdx.x*4 + w;
    int n = lane*2;
    float2 a0 = *(const float2*)&p0[(size_t)row*ld0 + n];
    float2 a1 = *(const float2*)&p1[(size_t)row*ld1 + n];
    float2 xv = *(const float2*)&x[(size_t)row*128 + n];
    float v0 = xv.x + (a0.x + a1.x + bias[n]);
    float v1 = xv.y + (a0.y + a1.y + bias[n+1]);
    *(float2*)&x[(size_t)row*128 + n] = make_float2(v0, v1);
    if (doLN) {
        double v0d = v0, v1d = v1;
        double sum = v0d + v1d, sq = v0d*v0d + v1d*v1d;
        #pragma unroll
        for (int o = 32; o > 0; o >>= 1) { sum += __shfl_xor(sum, o); sq += __shfl_xor(sq, o); }
        double mean = sum * (1.0/128.0);
        double var  = sq  * (1.0/128.0) - mean*mean;
        double inv  = 1.0 / sqrt(var + 1e-5);
        float2 o2;
        o2.x = (float)((v0d - mean)*inv*(double)ls[n]   + (double)lb[n]);
        o2.y = (float)((v1d - mean)*inv*(double)ls[n+1] + (double)lb[n+1]);
        *(float2*)&h[(size_t)row*128 + n] = o2;
    }
}

// ---------------- attention: block (b,h), 256 thr = 1 q-row each, branch-free ----------------
// All lanes read the SAME K/V row per iteration -> LDS broadcast, zero shuffles
// in the hot loop. q[32]+o[32] in regs (launch_bounds(256,2): 256-VGPR budget).
__global__ __launch_bounds__(256, 2) void attn_kernel(float* __restrict__ qkv)
{
    __shared__ float Ks[256*36];
    __shared__ float Vs[256*36];
    int tid = threadIdx.x;
    int b = blockIdx.x >> 2, h = blockIdx.x & 3;
    const float scale = 0.17677669529663687f;
    size_t rb = (size_t)(b*256 + tid) * 384;
    {   // stage own K/V row
        const float* kp = qkv + rb + 128 + h*32;
        const float* vp = qkv + rb + 256 + h*32;
        #pragma unroll
        for (int i = 0; i < 8; ++i) {
            *(float4*)&Ks[tid*36 + i*4] = *(const float4*)&kp[i*4];
            *(float4*)&Vs[tid*36 + i*4] = *(const float4*)&vp[i*4];
        }
    }
    float q[32];
    const float* qp = qkv + rb + h*32;
    #pragma unroll
    for (int i = 0; i < 32; ++i) q[i] = qp[i] * scale;
    __syncthreads();
    float o[32];
    #pragma unroll
    for (int i = 0; i < 32; ++i) o[i] = 0.f;
    float l = 0.f;
    for (int j = 0; j < 256; ++j) {
        const float* kr = &Ks[j*36];
        float s0 = 0.f, s1 = 0.f, s2 = 0.f, s3 = 0.f;   // 4-acc dot tree
        #pragma unroll
        for (int i = 0; i < 8; ++i) {
            s0 = fmaf(q[i],    kr[i],    s0);
            s1 = fmaf(q[8+i],  kr[8+i],  s1);
            s2 = fmaf(q[16+i], kr[16+i], s2);
            s3 = fmaf(q[24+i], kr[24+i], s3);
        }
        float e = __expf((s0 + s1) + (s2 + s3));
        l += e;
        const float* vr = &Vs[j*36];
        #pragma unroll
        for (int i = 0; i < 32; ++i) o[i] = fmaf(e, vr[i], o[i]);
    }
    float inv = 1.0f / l;
    float* op = qkv + rb + h*32;   // overwrite own q slot
    #pragma unroll
    for (int i = 0; i < 32; ++i) op[i] = o[i] * inv;
}

// ---------------- VQ: cc precompute ----------------
__global__ __launch_bounds__(256) void cc_kernel(const float* __restrict__ cb,
                                                 float* __restrict__ ccs)
{
    int c = blockIdx.x*256 + threadIdx.x;
    const float* p = cb + (size_t)c*128;
    float r[8];
    #pragma unroll
    for (int j = 0; j < 8; ++j) { float v = p[j]; r[j] = v*v; }
    for (int i = 8; i < 128; i += 8)
        #pragma unroll
        for (int j = 0; j < 8; ++j) { float v = p[i+j]; r[j] += v*v; }
    ccs[c] = ((r[0]+r[1]) + (r[2]+r[3])) + ((r[4]+r[5]) + (r[6]+r[7]));
}

#define ZC(k) (((k)&3)==0 ? z[(k)>>2].x : ((k)&3)==1 ? z[(k)>>2].y : ((k)&3)==2 ? z[(k)>>2].z : z[(k)>>2].w)

// ---------------- VQ distance pass ----------------
__global__ __launch_bounds__(128) void vq_dist_kernel(const float* __restrict__ x,
    const float* __restrict__ cb, const float* __restrict__ ccs,
    float* __restrict__ pbv, int* __restrict__ pbi)
{
    __shared__ float Cs[8192];
    __shared__ float ccl[64];
    int tid = threadIdx.x;
    int m = blockIdx.x*128 + tid;
    int split = blockIdx.y;
    int cbase = split*64;
    const float4* cbp = (const float4*)(cb + (size_t)cbase*128);
    for (int e = tid; e < 2048; e += 128) ((float4*)Cs)[e] = cbp[e];
    if (tid < 64) ccl[tid] = ccs[cbase + tid];
    float4 z[32];
    const float4* zp = (const float4*)(x + (size_t)m*128);
    #pragma unroll
    for (int i = 0; i < 32; ++i) z[i] = zp[i];
    float r[8];
    #pragma unroll
    for (int j = 0; j < 8; ++j) { float v = ZC(j); r[j] = v*v; }
    #pragma unroll
    for (int i = 8; i < 128; i += 8)
        #pragma unroll
        for (int j = 0; j < 8; ++j) { float v = ZC(i+j); r[j] += v*v; }
    float zz = ((r[0]+r[1]) + (r[2]+r[3])) + ((r[4]+r[5]) + (r[6]+r[7]));
    __syncthreads();
    float bestv = INFINITY;
    int   besti = 0;
    for (int g = 0; g < 16; ++g) {
        const float* c0 = &Cs[(g*4+0)*128];
        const float* c1 = &Cs[(g*4+1)*128];
        const float* c2 = &Cs[(g*4+2)*128];
        const float* c3 = &Cs[(g*4+3)*128];
        float a0 = 0.f, a1 = 0.f, a2 = 0.f, a3 = 0.f;
        #pragma unroll
        for (int q = 0; q < 32; ++q) {
            float4 v0 = *(const float4*)&c0[q*4];
            float4 v1 = *(const float4*)&c1[q*4];
            float4 v2 = *(const float4*)&c2[q*4];
            float4 v3 = *(const float4*)&c3[q*4];
            float4 zq = z[q];
            a0 = fmaf(zq.x, v0.x, a0); a0 = fmaf(zq.y, v0.y, a0);
            a0 = fmaf(zq.z, v0.z, a0); a0 = fmaf(zq.w, v0.w, a0);
            a1 = fmaf(zq.x, v1.x, a1); a1 = fmaf(zq.y, v1.y, a1);
            a1 = fmaf(zq.z, v1.z, a1); a1 = fmaf(zq.w, v1.w, a1);
            a2 = fmaf(zq.x, v2.x, a2); a2 = fmaf(zq.y, v2.y, a2);
            a2 = fmaf(zq.z, v2.z, a2); a2 = fmaf(zq.w, v2.w, a2);
            a3 = fmaf(zq.x, v3.x, a3); a3 = fmaf(zq.y, v3.y, a3);
            a3 = fmaf(zq.z, v3.z, a3); a3 = fmaf(zq.w, v3.w, a3);
        }
        int code = cbase + g*4;
        float t1, d;
        t1 = zz + ccl[g*4+0]; d = t1 - 2.0f*a0; if (d < bestv) { bestv = d; besti = code;   }
        t1 = zz + ccl[g*4+1]; d = t1 - 2.0f*a1; if (d < bestv) { bestv = d; besti = code+1; }
        t1 = zz + ccl[g*4+2]; d = t1 - 2.0f*a2; if (d < bestv) { bestv = d; besti = code+2; }
        t1 = zz + ccl[g*4+3]; d = t1 - 2.0f*a3; if (d < bestv) { bestv = d; besti = code+3; }
    }
    pbv[(size_t)split*16384 + m] = bestv;
    pbi[(size_t)split*16384 + m] = besti;
}

// ---------------- VQ merge: 512 blocks x 32 rows ----------------
__global__ __launch_bounds__(256) void vq_merge_kernel(const float* __restrict__ pbv,
    const int* __restrict__ pbi, const float* __restrict__ cb,
    float* __restrict__ quant, float* __restrict__ idxf, float* __restrict__ counts)
{
    __shared__ int fidx[32];
    int tid = threadIdx.x;
    int m0 = blockIdx.x*32;
    if (tid < 32) {
        int m = m0 + tid;
        float v = pbv[m]; int gi = pbi[m];
        #pragma unroll
        for (int s = 1; s < 8; ++s) {
            float vv = pbv[(size_t)s*16384 + m]; int ii = pbi[(size_t)s*16384 + m];
            if (vv < v) { v = vv; gi = ii; }
        }
        fidx[tid] = gi;
        idxf[m] = (float)gi;
        atomicAdd(&counts[gi], 1.0f);
    }
    __syncthreads();
    #pragma unroll
    for (int e0 = 0; e0 < 4; ++e0) {
        int e = e0*256 + tid;
        int rr = e >> 5, k4 = e & 31;
        ((float4*)&quant[(size_t)(m0+rr)*128])[k4] = ((const float4*)&cb[(size_t)fidx[rr]*128])[k4];
    }
}

// ---------------- gf + logits ----------------
__global__ __launch_bounds__(128) void gf_logits_kernel(const float* __restrict__ quant,
    const float* __restrict__ head_w, const float* __restrict__ head_b,
    float* __restrict__ gf, float* __restrict__ logits)
{
    int b = blockIdx.x, d = threadIdx.x;
    double s = 0.0;
    for (int n = 0; n < 256; ++n) s += (double)quant[(size_t)(b*256+n)*128 + d];
    double g = s * (1.0/256.0);
    gf[b*128 + d] = (float)g;
    __shared__ double gs[128];
    gs[d] = g;
    __syncthreads();
    if (d < 8) {
        double l = (double)head_b[d];
        for (int k = 0; k < 128; ++k) l += gs[k] * (double)head_w[d*128 + k];
        logits[b*8 + d] = (float)l;
    }
}

// ---------------- perplexity ----------------
__global__ __launch_bounds__(512) void perp_kernel(const float* __restrict__ counts,
                                                   float* __restrict__ out)
{
    __shared__ double sh[512];
    int t = threadIdx.x;
    double p = (double)counts[t] * (1.0/16384.0);
    sh[t] = p * log(p + 1e-10);
    __syncthreads();
    for (int s = 256; s > 0; s >>= 1) { if (t < s) sh[t] += sh[t+s]; __syncthreads(); }
    if (t == 0) out[0] = (float)exp(-sh[0]);
}

extern "C" void kernel_launch(void* const* d_in, const int* in_sizes, int n_in,
                              void* d_out, int out_size, void* d_ws, size_t ws_size,
                              hipStream_t stream)
{
    const float* image   = (const float*)d_in[0];
    const float* conv_w  = (const float*)d_in[1];
    const float* conv_b  = (const float*)d_in[2];
    const float* stat_w1 = (const float*)d_in[3];
    const float* stat_b1 = (const float*)d_in[4];
    const float* stat_w2 = (const float*)d_in[5];
    const float* stat_b2 = (const float*)d_in[6];
    const float* pos     = (const float*)d_in[7];
    const float* ln1_s   = (const float*)d_in[8];
    const float* ln1_b   = (const float*)d_in[9];
    const float* qkv_w   = (const float*)d_in[10];
    const float* qkv_b   = (const float*)d_in[11];
    const float* out_w   = (const float*)d_in[12];
    const float* out_b   = (const float*)d_in[13];
    const float* ln2_s   = (const float*)d_in[14];
    const float* ln2_b   = (const float*)d_in[15];
    const float* ff1_w   = (const float*)d_in[16];
    const float* ff1_b   = (const float*)d_in[17];
    const float* ff2_w   = (const float*)d_in[18];
    const float* ff2_b   = (const float*)d_in[19];
    const float* codebook= (const float*)d_in[20];
    const float* head_w  = (const float*)d_in[21];
    const float* head_b  = (const float*)d_in[22];

    char* wsb = (char*)d_ws;
    float*  x32   = (float*) (wsb);                            //  8,388,608 B
    float*  h32   = (float*) (wsb + 8388608);                  //  8,388,608 B
    float*  qkv32 = (float*) (wsb + 16777216);                 // 25,165,824 B
    double* sf64  = (double*)(wsb + 41943040);                 //     65,536 B
    double* feats = (double*)(wsb + 42008576);                 //      7,680 B
    float*  counts= (float*) (wsb + 42016256);                 //      2,048 B
    double* part  = (double*)(wsb + 42018304);                 //    278,528 B
    float*  pbv   = (float*) (wsb + 42296832);                 //    524,288 B
    int*    pbi   = (int*)   (wsb + 42821120);                 //    524,288 B
    float*  ccs   = (float*) (wsb + 43345408);                 //      2,048 B

    float* outf   = (float*)d_out;
    float* quant  = outf;
    float* idxf   = quant + 2097152;
    float* logits = idxf + 16384;
    float* gf     = logits + 512;
    float* perp   = gf + 8192;

    hipMemsetAsync(counts, 0, 512*sizeof(float), stream);

    stats_partial_kernel<<<2048, 256, 0, stream>>>(image, part);
    stats_final_kernel<<<64, 32, 0, stream>>>(part, feats);
    sfmlp_kernel<<<64, 128, 0, stream>>>(feats, stat_w1, stat_b1, stat_w2, stat_b2, sf64);
    cc_kernel<<<2, 256, 0, stream>>>(codebook, ccs);

    patch_sk_kernel<<<dim3(256, 2, 4), 256, 0, stream>>>(image, conv_w, qkv32, h32);
    cpatch_kernel<<<4096, 256, 0, stream>>>(qkv32, h32, conv_b, pos, sf64,
                                            ln1_s, ln1_b, x32, h32);

    for (int i = 0; i < 2; ++i) {
        gemm_kernel<<<dim3(256, 6), 256, 0, stream>>>(h32, 128, qkv_w + (size_t)i*384*128,
                                                      qkv_b + i*384, qkv32, 16384, 384, 128, 0);
        attn_kernel<<<256, 256, 0, stream>>>(qkv32);
        gemm_sk_kernel<<<dim3(256, 2, 2), 256, 0, stream>>>(qkv32, 384,
                                                            out_w + (size_t)i*128*128, 128, 64,
                                                            qkv32 + 128, qkv32 + 256, 384);
        cres_kernel<<<4096, 256, 0, stream>>>(x32, qkv32 + 128, 384, qkv32 + 256, 384,
                                              out_b + i*128, ln2_s + i*128, ln2_b + i*128,
                                              h32, 1);
        gemm_kernel<<<dim3(256, 4), 256, 0, stream>>>(h32, 128, ff1_w + (size_t)i*256*128,
                                                      ff1_b + i*256, qkv32, 16384, 256, 128, 2);
        gemm_sk_kernel<<<dim3(256, 2, 2), 256, 0, stream>>>(qkv32, 256,
                                                            ff2_w + (size_t)i*128*256, 256, 128,
                                                            qkv32 + 4194304, h32, 128);
        cres_kernel<<<4096, 256, 0, stream>>>(x32, qkv32 + 4194304, 128, h32, 128,
                                              ff2_b + i*128, ln1_s + 128, ln1_b + 128,
                                              h32, i == 0 ? 1 : 0);
    }

    vq_dist_kernel<<<dim3(128, 8), 128, 0, stream>>>(x32, codebook, ccs, pbv, pbi);
    vq_merge_kernel<<<512, 256, 0, stream>>>(pbv, pbi, codebook, quant, idxf, counts);
    gf_logits_kernel<<<64, 128, 0, stream>>>(quant, head_w, head_b, gf, logits);
    perp_kernel<<<1, 512, 0, stream>>>(counts, perp);
}

// Round 21
// 502.983 us; speedup vs baseline: 1.0443x; 1.0443x over previous
//
#include <hip/hip_runtime.h>
#include <math.h>

__device__ __forceinline__ void gload16(const float* g, float* l) {
    __builtin_amdgcn_global_load_lds(
        (const __attribute__((address_space(1))) void*)g,
        (__attribute__((address_space(3))) void*)l, 16, 0, 0);
}

// ---------------- stats phase 1 ----------------
__device__ __forceinline__ double wred_add(double v) {
    #pragma unroll
    for (int o = 32; o > 0; o >>= 1) v += __shfl_xor(v, o);
    return v;
}
__device__ __forceinline__ float wred_min(float v) {
    #pragma unroll
    for (int o = 32; o > 0; o >>= 1) v = fminf(v, __shfl_xor(v, o));
    return v;
}
__device__ __forceinline__ float wred_max(float v) {
    #pragma unroll
    for (int o = 32; o > 0; o >>= 1) v = fmaxf(v, __shfl_xor(v, o));
    return v;
}

#define PREC 17

__global__ __launch_bounds__(256) void stats_partial_kernel(const float* __restrict__ img,
                                                            double* __restrict__ part)
{
    int b = blockIdx.x >> 5, blk = blockIdx.x & 31;
    int tid = threadIdx.x;
    const float* r0 = img + (size_t)b * 3 * 65536;
    const float* g0 = r0 + 65536;
    const float* b0 = r0 + 131072;
    int base = blk*2048 + tid*8;
    double s0=0,s1=0,s2=0,q0=0,q1=0,q2=0,l1=0,l2=0,l3=0,l4=0,dark=0;
    float mn0=1e30f,mn1=1e30f,mn2=1e30f, mx0=-1e30f,mx1=-1e30f,mx2=-1e30f;
    #pragma unroll
    for (int u = 0; u < 2; ++u) {
        float4 rv = *(const float4*)&r0[base + u*4];
        float4 gv = *(const float4*)&g0[base + u*4];
        float4 bv = *(const float4*)&b0[base + u*4];
        float rr[4] = {rv.x, rv.y, rv.z, rv.w};
        float gg[4] = {gv.x, gv.y, gv.z, gv.w};
        float bbv[4] = {bv.x, bv.y, bv.z, bv.w};
        #pragma unroll
        for (int e = 0; e < 4; ++e) {
            float r = rr[e], g = gg[e], bl = bbv[e];
            double rd_ = r, gd = g, bd = bl;
            s0 += rd_; q0 += rd_*rd_; mn0 = fminf(mn0, r); mx0 = fmaxf(mx0, r);
            s1 += gd;  q1 += gd*gd;   mn1 = fminf(mn1, g); mx1 = fmaxf(mx1, g);
            s2 += bd;  q2 += bd*bd;   mn2 = fminf(mn2, bl); mx2 = fmaxf(mx2, bl);
            double lum = 0.299*rd_ + 0.587*gd + 0.114*bd;
            double d2 = lum*lum;
            l1 += lum; l2 += d2; l3 += d2*lum; l4 += d2*d2;
            if (lum < 0.2) dark += 1.0;
        }
    }
    double dv[11] = {s0,s1,s2,q0,q1,q2,l1,l2,l3,l4,dark};
    #pragma unroll
    for (int q = 0; q < 11; ++q) dv[q] = wred_add(dv[q]);
    mn0 = wred_min(mn0); mn1 = wred_min(mn1); mn2 = wred_min(mn2);
    mx0 = wred_max(mx0); mx1 = wred_max(mx1); mx2 = wred_max(mx2);
    __shared__ double sd[4][PREC];
    int w = tid >> 6, lane = tid & 63;
    if (lane == 0) {
        #pragma unroll
        for (int q = 0; q < 11; ++q) sd[w][q] = dv[q];
        sd[w][11] = (double)mn0; sd[w][12] = (double)mn1; sd[w][13] = (double)mn2;
        sd[w][14] = (double)mx0; sd[w][15] = (double)mx1; sd[w][16] = (double)mx2;
    }
    __syncthreads();
    if (tid == 0) {
        double out[PREC];
        #pragma unroll
        for (int q = 0; q < PREC; ++q) out[q] = sd[0][q];
        #pragma unroll
        for (int ww = 1; ww < 4; ++ww) {
            #pragma unroll
            for (int q = 0; q < 11; ++q) out[q] += sd[ww][q];
            out[11] = fmin(out[11], sd[ww][11]); out[12] = fmin(out[12], sd[ww][12]);
            out[13] = fmin(out[13], sd[ww][13]);
            out[14] = fmax(out[14], sd[ww][14]); out[15] = fmax(out[15], sd[ww][15]);
            out[16] = fmax(out[16], sd[ww][16]);
        }
        double* p = part + (size_t)(b*32 + blk)*PREC;
        #pragma unroll
        for (int q = 0; q < PREC; ++q) p[q] = out[q];
    }
}

// ---------------- stats phase 2 ----------------
__global__ __launch_bounds__(32) void stats_final_kernel(const double* __restrict__ part,
                                                         double* __restrict__ feats)
{
    int b = blockIdx.x, t = threadIdx.x;
    const double* p = part + (size_t)(b*32 + t)*PREC;
    double v[PREC];
    #pragma unroll
    for (int q = 0; q < PREC; ++q) v[q] = p[q];
    #pragma unroll
    for (int o = 16; o > 0; o >>= 1) {
        #pragma unroll
        for (int q = 0; q < 11; ++q) v[q] += __shfl_xor(v[q], o);
        #pragma unroll
        for (int q = 11; q < 14; ++q) v[q] = fmin(v[q], __shfl_xor(v[q], o));
        #pragma unroll
        for (int q = 14; q < PREC; ++q) v[q] = fmax(v[q], __shfl_xor(v[q], o));
    }
    if (t == 0) {
        const double n = 65536.0;
        double* f = feats + b*15;
        for (int c = 0; c < 3; ++c) {
            double su = v[c], sq = v[3+c];
            f[c]   = su/n;
            f[3+c] = sqrt((sq - su*su/n) / (n - 1.0));
            f[6+c] = v[11+c];
            f[9+c] = v[14+c];
        }
        double m1 = v[6]/n, m2 = v[7]/n, m3 = v[8]/n, m4 = v[9]/n;
        double mu2 = m2 - m1*m1;
        double mu3 = m3 - 3.0*m1*m2 + 2.0*m1*m1*m1;
        double mu4 = m4 - 4.0*m1*m3 + 6.0*m1*m1*m2 - 3.0*m1*m1*m1*m1;
        double sd = sqrt(mu2);
        f[12] = mu3 / (sd*sd*sd + 1e-6);
        f[13] = mu4 / (sd*sd*sd*sd + 1e-6);
        f[14] = v[10] / n;
    }
}

// ---------------- stat MLP ----------------
__global__ __launch_bounds__(128) void sfmlp_kernel(const double* __restrict__ feats,
    const float* __restrict__ w1, const float* __restrict__ b1,
    const float* __restrict__ w2, const float* __restrict__ b2,
    double* __restrict__ sf)
{
    int b = blockIdx.x, t = threadIdx.x;
    __shared__ double fs[15];
    __shared__ double hs[128];
    if (t < 15) fs[t] = feats[b*15 + t];
    __syncthreads();
    double h = (double)b1[t];
    for (int j = 0; j < 15; ++j) h += fs[j] * (double)w1[t*15 + j];
    hs[t] = fmax(h, 0.0);
    __syncthreads();
    double o = (double)b2[t];
    for (int j = 0; j < 128; ++j) o += hs[j] * (double)w2[t*128 + j];
    sf[b*128 + t] = o;
}

__device__ __forceinline__ int swz64(int r, int kq4) {
    return r*64 + (((kq4) ^ (r & 15)) << 2);
}

// ---------------- patch embedding split-K x4 gather-GEMM ----------------
__global__ __launch_bounds__(256) void patch_sk_kernel(const float* __restrict__ img,
    const float* __restrict__ w, float* __restrict__ Pa, float* __restrict__ Pb4)
{
    __shared__ float As[4096];
    __shared__ float Ws[4096];
    int tid = threadIdx.x;
    int tx = tid & 15, ty = tid >> 4;
    int m0 = blockIdx.x * 64, n0 = blockIdx.y * 64;
    int z = blockIdx.z;
    int kbase = z * 192;
    int wv = tid >> 6;
    float acc[4][4] = {};
    for (int k0 = 0; k0 < 192; k0 += 64) {
        #pragma unroll
        for (int call = 0; call < 4; ++call) {
            int s = call*256 + tid;
            int row = s >> 4, kq = (s & 15) ^ (row & 15);
            int m = m0 + row;
            int bb = m >> 8, pat = m & 255;
            int gy = pat >> 4, gx = pat & 15;
            int k = kbase + k0 + kq*4;
            int c = k >> 8, rem = k & 255;
            int py = rem >> 4, px = rem & 15;
            gload16(&img[(size_t)(bb*3 + c)*65536 + (size_t)(gy*16+py)*256 + gx*16 + px],
                    As + (call*256 + wv*64)*4);
            gload16(&w[(size_t)(n0+row)*768 + k], Ws + (call*256 + wv*64)*4);
        }
        __syncthreads();
        #pragma unroll 8
        for (int q = 0; q < 16; ++q) {
            float4 a4[4], w4[4];
            #pragma unroll
            for (int i=0;i<4;++i) a4[i] = *(const float4*)&As[swz64(ty + 16*i, q)];
            #pragma unroll
            for (int j=0;j<4;++j) w4[j] = *(const float4*)&Ws[swz64(tx + 16*j, q)];
            #pragma unroll
            for (int i=0;i<4;++i)
                #pragma unroll
                for (int j=0;j<4;++j) {
                    acc[i][j] = fmaf(a4[i].x, w4[j].x, acc[i][j]);
                    acc[i][j] = fmaf(a4[i].y, w4[j].y, acc[i][j]);
                    acc[i][j] = fmaf(a4[i].z, w4[j].z, acc[i][j]);
                    acc[i][j] = fmaf(a4[i].w, w4[j].w, acc[i][j]);
                }
        }
        __syncthreads();
    }
    float* P = (z < 3) ? (Pa + (size_t)z*2097152) : Pb4;
    #pragma unroll
    for (int i=0;i<4;++i){
        int m = m0 + ty + 16*i;
        #pragma unroll
        for (int j=0;j<4;++j){
            int n = n0 + tx + 16*j;
            P[(size_t)m*128 + n] = acc[i][j];
        }
    }
}

// ---------------- f32 GEMM (global_load_lds staging), epi 0=store+bias, 2=gelu ----------------
__global__ __launch_bounds__(256) void gemm_kernel(const float* __restrict__ A, int lda,
    const float* __restrict__ W, const float* __restrict__ bias,
    float* __restrict__ C, int M, int N, int K, int epi)
{
    __shared__ float As[4096];
    __shared__ float Ws[4096];
    int tid = threadIdx.x;
    int tx = tid & 15, ty = tid >> 4;
    int m0 = blockIdx.x * 64, n0 = blockIdx.y * 64;
    int wv = tid >> 6;
    float acc[4][4] = {};
    for (int k0 = 0; k0 < K; k0 += 64) {
        #pragma unroll
        for (int call = 0; call < 4; ++call) {
            int s = call*256 + tid;
            int row = s >> 4, kq = (s & 15) ^ (row & 15);
            gload16(&A[(size_t)(m0+row)*lda + k0 + kq*4], As + (call*256 + wv*64)*4);
            gload16(&W[(size_t)(n0+row)*K + k0 + kq*4], Ws + (call*256 + wv*64)*4);
        }
        __syncthreads();
        #pragma unroll 8
        for (int q = 0; q < 16; ++q) {
            float4 a4[4], w4[4];
            #pragma unroll
            for (int i=0;i<4;++i) a4[i] = *(const float4*)&As[swz64(ty + 16*i, q)];
            #pragma unroll
            for (int j=0;j<4;++j) w4[j] = *(const float4*)&Ws[swz64(tx + 16*j, q)];
            #pragma unroll
            for (int i=0;i<4;++i)
                #pragma unroll
                for (int j=0;j<4;++j) {
                    acc[i][j] = fmaf(a4[i].x, w4[j].x, acc[i][j]);
                    acc[i][j] = fmaf(a4[i].y, w4[j].y, acc[i][j]);
                    acc[i][j] = fmaf(a4[i].z, w4[j].z, acc[i][j]);
                    acc[i][j] = fmaf(a4[i].w, w4[j].w, acc[i][j]);
                }
        }
        __syncthreads();
    }
    #pragma unroll
    for (int i=0;i<4;++i){
        int m = m0 + ty + 16*i;
        #pragma unroll
        for (int j=0;j<4;++j){
            int n = n0 + tx + 16*j;
            float v = acc[i][j] + bias[n];
            if (epi == 0) {
                C[(size_t)m*N + n] = v;
            } else {
                C[(size_t)m*N + n] = 0.5f*v*(1.0f + erff(v*0.70710678118654752f));
            }
        }
    }
}

// ---------------- split-K f32 GEMM ----------------
__global__ __launch_bounds__(256) void gemm_sk_kernel(const float* __restrict__ A, int lda,
    const float* __restrict__ W, int K, int K2,
    float* __restrict__ P0, float* __restrict__ P1, int ldo)
{
    __shared__ float As[4096];
    __shared__ float Ws[4096];
    int tid = threadIdx.x;
    int tx = tid & 15, ty = tid >> 4;
    int m0 = blockIdx.x * 64, n0 = blockIdx.y * 64;
    int kbase = blockIdx.z * K2;
    int wv = tid >> 6;
    float acc[4][4] = {};
    for (int k0 = 0; k0 < K2; k0 += 64) {
        #pragma unroll
        for (int call = 0; call < 4; ++call) {
            int s = call*256 + tid;
            int row = s >> 4, kq = (s & 15) ^ (row & 15);
            gload16(&A[(size_t)(m0+row)*lda + kbase + k0 + kq*4], As + (call*256 + wv*64)*4);
            gload16(&W[(size_t)(n0+row)*K + kbase + k0 + kq*4], Ws + (call*256 + wv*64)*4);
        }
        __syncthreads();
        #pragma unroll 8
        for (int q = 0; q < 16; ++q) {
            float4 a4[4], w4[4];
            #pragma unroll
            for (int i=0;i<4;++i) a4[i] = *(const float4*)&As[swz64(ty + 16*i, q)];
            #pragma unroll
            for (int j=0;j<4;++j) w4[j] = *(const float4*)&Ws[swz64(tx + 16*j, q)];
            #pragma unroll
            for (int i=0;i<4;++i)
                #pragma unroll
                for (int j=0;j<4;++j) {
                    acc[i][j] = fmaf(a4[i].x, w4[j].x, acc[i][j]);
                    acc[i][j] = fmaf(a4[i].y, w4[j].y, acc[i][j]);
                    acc[i][j] = fmaf(a4[i].z, w4[j].z, acc[i][j]);
                    acc[i][j] = fmaf(a4[i].w, w4[j].w, acc[i][j]);
                }
        }
        __syncthreads();
    }
    float* P = blockIdx.z ? P1 : P0;
    #pragma unroll
    for (int i=0;i<4;++i){
        int m = m0 + ty + 16*i;
        #pragma unroll
        for (int j=0;j<4;++j){
            int n = n0 + tx + 16*j;
            P[(size_t)m*ldo + n] = acc[i][j];
        }
    }
}

// ---------------- combine: x = (((p0+p1)+p2)+p3)+bias+pos+sf ; h = LN(x) ----------------
__global__ __launch_bounds__(256) void cpatch_kernel(const float* __restrict__ pa,
    const float* __restrict__ p3, const float* __restrict__ bias,
    const float* __restrict__ pos, const double* __restrict__ sf,
    const float* __restrict__ ls, const float* __restrict__ lb,
    float* __restrict__ x, float* __restrict__ h)
{
    int tid = threadIdx.x;
    int lane = tid & 63, w = tid >> 6;
    int row = blockIdx.x*4 + w;
    int bb = row >> 8, pat = row & 255;
    int n = lane*2;
    float2 a0 = *(const float2*)&pa[(size_t)row*128 + n];
    float2 a1 = *(const float2*)&pa[2097152 + (size_t)row*128 + n];
    float2 a2 = *(const float2*)&pa[4194304 + (size_t)row*128 + n];
    float2 a3 = *(const float2*)&p3[(size_t)row*128 + n];
    float v0 = ((a0.x + a1.x) + a2.x) + a3.x + bias[n]   + pos[pat*128 + n]   + (float)sf[bb*128 + n];
    float v1 = ((a0.y + a1.y) + a2.y) + a3.y + bias[n+1] + pos[pat*128 + n+1] + (float)sf[bb*128 + n+1];
    *(float2*)&x[(size_t)row*128 + n] = make_float2(v0, v1);
    double v0d = v0, v1d = v1;
    double sum = v0d + v1d, sq = v0d*v0d + v1d*v1d;
    #pragma unroll
    for (int o = 32; o > 0; o >>= 1) { sum += __shfl_xor(sum, o); sq += __shfl_xor(sq, o); }
    double mean = sum * (1.0/128.0);
    double var  = sq  * (1.0/128.0) - mean*mean;
    double inv  = 1.0 / sqrt(var + 1e-5);
    float2 o2;
    o2.x = (float)((v0d - mean)*inv*(double)ls[n]   + (double)lb[n]);
    o2.y = (float)((v1d - mean)*inv*(double)ls[n+1] + (double)lb[n+1]);
    *(float2*)&h[(size_t)row*128 + n] = o2;
}

// ---------------- combine: x += (p0+p1)+bias ; optional h = LN(x) ----------------
__global__ __launch_bounds__(256) void cres_kernel(float* __restrict__ x,
    const float* __restrict__ p0, int ld0, const float* __restrict__ p1, int ld1,
    const float* __restrict__ bias,
    const float* __restrict__ ls, const float* __restrict__ lb,
    float* __restrict__ h, int doLN)
{
    int tid = threadIdx.x;
    int lane = tid & 63, w = tid >> 6;
    int row = blockIdx.x*4 + w;
    int n = lane*2;
    float2 a0 = *(const float2*)&p0[(size_t)row*ld0 + n];
    float2 a1 = *(const float2*)&p1[(size_t)row*ld1 + n];
    float2 xv = *(const float2*)&x[(size_t)row*128 + n];
    float v0 = xv.x + (a0.x + a1.x + bias[n]);
    float v1 = xv.y + (a0.y + a1.y + bias[n+1]);
    *(float2*)&x[(size_t)row*128 + n] = make_float2(v0, v1);
    if (doLN) {
        double v0d = v0, v1d = v1;
        double sum = v0d + v1d, sq = v0d*v0d + v1d*v1d;
        #pragma unroll
        for (int o = 32; o > 0; o >>= 1) { sum += __shfl_xor(sum, o); sq += __shfl_xor(sq, o); }
        double mean = sum * (1.0/128.0);
        double var  = sq  * (1.0/128.0) - mean*mean;
        double inv  = 1.0 / sqrt(var + 1e-5);
        float2 o2;
        o2.x = (float)((v0d - mean)*inv*(double)ls[n]   + (double)lb[n]);
        o2.y = (float)((v1d - mean)*inv*(double)ls[n+1] + (double)lb[n+1]);
        *(float2*)&h[(size_t)row*128 + n] = o2;
    }
}

// ---------------- attention: block (b,h,half), 512 thr, branch-free softmax ----------------
// (Best-known config: R17/R18, ~46 us. 2 blocks/CU x 8 waves.)
__global__ __launch_bounds__(512, 4) void attn_kernel(float* __restrict__ qkv)
{
    __shared__ float Ks[256*36];
    __shared__ float Vs[256*36];
    int tid = threadIdx.x;
    int b = blockIdx.x >> 3, h = (blockIdx.x >> 1) & 3, half = blockIdx.x & 1;
    {
        int row = tid >> 1, p16 = (tid & 1) * 16;
        size_t rb = (size_t)(b*256 + row) * 384;
        const float* kp = qkv + rb + 128 + h*32 + p16;
        const float* vp = qkv + rb + 256 + h*32 + p16;
        #pragma unroll
        for (int i = 0; i < 4; ++i) {
            *(float4*)&Ks[row*36 + p16 + i*4] = *(const float4*)&kp[i*4];
            *(float4*)&Vs[row*36 + p16 + i*4] = *(const float4*)&vp[i*4];
        }
    }
    int qrow = half*128 + (tid >> 2);
    int ds = (tid >> 1) & 1;
    int ks = tid & 1;
    const float scale = 0.17677669529663687f;
    float q[16];
    const float* qp = qkv + (size_t)(b*256 + qrow)*384 + h*32 + ds*16;
    #pragma unroll
    for (int i = 0; i < 16; ++i) q[i] = qp[i] * scale;
    __syncthreads();
    float o[16];
    #pragma unroll
    for (int i = 0; i < 16; ++i) o[i] = 0.f;
    float l = 0.f;
    for (int it = 0; it < 128; ++it) {
        int j = it*2 + ks;
        const float* kr = &Ks[j*36 + ds*16];
        float s = 0.f;
        #pragma unroll
        for (int i = 0; i < 16; ++i) s = fmaf(q[i], kr[i], s);
        s += __shfl_xor(s, 2);
        float e = __expf(s);
        l += e;
        const float* vr = &Vs[j*36 + ds*16];
        #pragma unroll
        for (int i = 0; i < 16; ++i) o[i] = fmaf(e, vr[i], o[i]);
    }
    l += __shfl_xor(l, 1);
    #pragma unroll
    for (int i = 0; i < 16; ++i) o[i] += __shfl_xor(o[i], 1);
    if (ks == 0) {
        float inv = 1.0f / l;
        float* op = qkv + (size_t)(b*256 + qrow)*384 + h*32 + ds*16;
        #pragma unroll
        for (int i = 0; i < 16; ++i) op[i] = o[i] * inv;
    }
}

// ---------------- VQ: cc precompute ----------------
__global__ __launch_bounds__(256) void cc_kernel(const float* __restrict__ cb,
                                                 float* __restrict__ ccs)
{
    int c = blockIdx.x*256 + threadIdx.x;
    const float* p = cb + (size_t)c*128;
    float r[8];
    #pragma unroll
    for (int j = 0; j < 8; ++j) { float v = p[j]; r[j] = v*v; }
    for (int i = 8; i < 128; i += 8)
        #pragma unroll
        for (int j = 0; j < 8; ++j) { float v = p[i+j]; r[j] += v*v; }
    ccs[c] = ((r[0]+r[1]) + (r[2]+r[3])) + ((r[4]+r[5]) + (r[6]+r[7]));
}

#define ZC(k) (((k)&3)==0 ? z[(k)>>2].x : ((k)&3)==1 ? z[(k)>>2].y : ((k)&3)==2 ? z[(k)>>2].z : z[(k)>>2].w)

// ---------------- VQ distance pass ----------------
__global__ __launch_bounds__(128) void vq_dist_kernel(const float* __restrict__ x,
    const float* __restrict__ cb, const float* __restrict__ ccs,
    float* __restrict__ pbv, int* __restrict__ pbi)
{
    __shared__ float Cs[8192];
    __shared__ float ccl[64];
    int tid = threadIdx.x;
    int m = blockIdx.x*128 + tid;
    int split = blockIdx.y;
    int cbase = split*64;
    const float4* cbp = (const float4*)(cb + (size_t)cbase*128);
    for (int e = tid; e < 2048; e += 128) ((float4*)Cs)[e] = cbp[e];
    if (tid < 64) ccl[tid] = ccs[cbase + tid];
    float4 z[32];
    const float4* zp = (const float4*)(x + (size_t)m*128);
    #pragma unroll
    for (int i = 0; i < 32; ++i) z[i] = zp[i];
    float r[8];
    #pragma unroll
    for (int j = 0; j < 8; ++j) { float v = ZC(j); r[j] = v*v; }
    #pragma unroll
    for (int i = 8; i < 128; i += 8)
        #pragma unroll
        for (int j = 0; j < 8; ++j) { float v = ZC(i+j); r[j] += v*v; }
    float zz = ((r[0]+r[1]) + (r[2]+r[3])) + ((r[4]+r[5]) + (r[6]+r[7]));
    __syncthreads();
    float bestv = INFINITY;
    int   besti = 0;
    for (int g = 0; g < 16; ++g) {
        const float* c0 = &Cs[(g*4+0)*128];
        const float* c1 = &Cs[(g*4+1)*128];
        const float* c2 = &Cs[(g*4+2)*128];
        const float* c3 = &Cs[(g*4+3)*128];
        float a0 = 0.f, a1 = 0.f, a2 = 0.f, a3 = 0.f;
        #pragma unroll
        for (int q = 0; q < 32; ++q) {
            float4 v0 = *(const float4*)&c0[q*4];
            float4 v1 = *(const float4*)&c1[q*4];
            float4 v2 = *(const float4*)&c2[q*4];
            float4 v3 = *(const float4*)&c3[q*4];
            float4 zq = z[q];
            a0 = fmaf(zq.x, v0.x, a0); a0 = fmaf(zq.y, v0.y, a0);
            a0 = fmaf(zq.z, v0.z, a0); a0 = fmaf(zq.w, v0.w, a0);
            a1 = fmaf(zq.x, v1.x, a1); a1 = fmaf(zq.y, v1.y, a1);
            a1 = fmaf(zq.z, v1.z, a1); a1 = fmaf(zq.w, v1.w, a1);
            a2 = fmaf(zq.x, v2.x, a2); a2 = fmaf(zq.y, v2.y, a2);
            a2 = fmaf(zq.z, v2.z, a2); a2 = fmaf(zq.w, v2.w, a2);
            a3 = fmaf(zq.x, v3.x, a3); a3 = fmaf(zq.y, v3.y, a3);
            a3 = fmaf(zq.z, v3.z, a3); a3 = fmaf(zq.w, v3.w, a3);
        }
        int code = cbase + g*4;
        float t1, d;
        t1 = zz + ccl[g*4+0]; d = t1 - 2.0f*a0; if (d < bestv) { bestv = d; besti = code;   }
        t1 = zz + ccl[g*4+1]; d = t1 - 2.0f*a1; if (d < bestv) { bestv = d; besti = code+1; }
        t1 = zz + ccl[g*4+2]; d = t1 - 2.0f*a2; if (d < bestv) { bestv = d; besti = code+2; }
        t1 = zz + ccl[g*4+3]; d = t1 - 2.0f*a3; if (d < bestv) { bestv = d; besti = code+3; }
    }
    pbv[(size_t)split*16384 + m] = bestv;
    pbi[(size_t)split*16384 + m] = besti;
}

// ---------------- VQ merge: 512 blocks x 32 rows ----------------
__global__ __launch_bounds__(256) void vq_merge_kernel(const float* __restrict__ pbv,
    const int* __restrict__ pbi, const float* __restrict__ cb,
    float* __restrict__ quant, float* __restrict__ idxf, float* __restrict__ counts)
{
    __shared__ int fidx[32];
    int tid = threadIdx.x;
    int m0 = blockIdx.x*32;
    if (tid < 32) {
        int m = m0 + tid;
        float v = pbv[m]; int gi = pbi[m];
        #pragma unroll
        for (int s = 1; s < 8; ++s) {
            float vv = pbv[(size_t)s*16384 + m]; int ii = pbi[(size_t)s*16384 + m];
            if (vv < v) { v = vv; gi = ii; }
        }
        fidx[tid] = gi;
        idxf[m] = (float)gi;
        atomicAdd(&counts[gi], 1.0f);
    }
    __syncthreads();
    #pragma unroll
    for (int e0 = 0; e0 < 4; ++e0) {
        int e = e0*256 + tid;
        int rr = e >> 5, k4 = e & 31;
        ((float4*)&quant[(size_t)(m0+rr)*128])[k4] = ((const float4*)&cb[(size_t)fidx[rr]*128])[k4];
    }
}

// ---------------- gf + logits ----------------
__global__ __launch_bounds__(128) void gf_logits_kernel(const float* __restrict__ quant,
    const float* __restrict__ head_w, const float* __restrict__ head_b,
    float* __restrict__ gf, float* __restrict__ logits)
{
    int b = blockIdx.x, d = threadIdx.x;
    double s = 0.0;
    for (int n = 0; n < 256; ++n) s += (double)quant[(size_t)(b*256+n)*128 + d];
    double g = s * (1.0/256.0);
    gf[b*128 + d] = (float)g;
    __shared__ double gs[128];
    gs[d] = g;
    __syncthreads();
    if (d < 8) {
        double l = (double)head_b[d];
        for (int k = 0; k < 128; ++k) l += gs[k] * (double)head_w[d*128 + k];
        logits[b*8 + d] = (float)l;
    }
}

// ---------------- perplexity ----------------
__global__ __launch_bounds__(512) void perp_kernel(const float* __restrict__ counts,
                                                   float* __restrict__ out)
{
    __shared__ double sh[512];
    int t = threadIdx.x;
    double p = (double)counts[t] * (1.0/16384.0);
    sh[t] = p * log(p + 1e-10);
    __syncthreads();
    for (int s = 256; s > 0; s >>= 1) { if (t < s) sh[t] += sh[t+s]; __syncthreads(); }
    if (t == 0) out[0] = (float)exp(-sh[0]);
}

extern "C" void kernel_launch(void* const* d_in, const int* in_sizes, int n_in,
                              void* d_out, int out_size, void* d_ws, size_t ws_size,
                              hipStream_t stream)
{
    const float* image   = (const float*)d_in[0];
    const float* conv_w  = (const float*)d_in[1];
    const float* conv_b  = (const float*)d_in[2];
    const float* stat_w1 = (const float*)d_in[3];
    const float* stat_b1 = (const float*)d_in[4];
    const float* stat_w2 = (const float*)d_in[5];
    const float* stat_b2 = (const float*)d_in[6];
    const float* pos     = (const float*)d_in[7];
    const float* ln1_s   = (const float*)d_in[8];
    const float* ln1_b   = (const float*)d_in[9];
    const float* qkv_w   = (const float*)d_in[10];
    const float* qkv_b   = (const float*)d_in[11];
    const float* out_w   = (const float*)d_in[12];
    const float* out_b   = (const float*)d_in[13];
    const float* ln2_s   = (const float*)d_in[14];
    const float* ln2_b   = (const float*)d_in[15];
    const float* ff1_w   = (const float*)d_in[16];
    const float* ff1_b   = (const float*)d_in[17];
    const float* ff2_w   = (const float*)d_in[18];
    const float* ff2_b   = (const float*)d_in[19];
    const float* codebook= (const float*)d_in[20];
    const float* head_w  = (const float*)d_in[21];
    const float* head_b  = (const float*)d_in[22];

    char* wsb = (char*)d_ws;
    float*  x32   = (float*) (wsb);                            //  8,388,608 B
    float*  h32   = (float*) (wsb + 8388608);                  //  8,388,608 B
    float*  qkv32 = (float*) (wsb + 16777216);                 // 25,165,824 B
    double* sf64  = (double*)(wsb + 41943040);                 //     65,536 B
    double* feats = (double*)(wsb + 42008576);                 //      7,680 B
    float*  counts= (float*) (wsb + 42016256);                 //      2,048 B
    double* part  = (double*)(wsb + 42018304);                 //    278,528 B
    float*  pbv   = (float*) (wsb + 42296832);                 //    524,288 B
    int*    pbi   = (int*)   (wsb + 42821120);                 //    524,288 B
    float*  ccs   = (float*) (wsb + 43345408);                 //      2,048 B

    float* outf   = (float*)d_out;
    float* quant  = outf;
    float* idxf   = quant + 2097152;
    float* logits = idxf + 16384;
    float* gf     = logits + 512;
    float* perp   = gf + 8192;

    hipMemsetAsync(counts, 0, 512*sizeof(float), stream);

    stats_partial_kernel<<<2048, 256, 0, stream>>>(image, part);
    stats_final_kernel<<<64, 32, 0, stream>>>(part, feats);
    sfmlp_kernel<<<64, 128, 0, stream>>>(feats, stat_w1, stat_b1, stat_w2, stat_b2, sf64);
    cc_kernel<<<2, 256, 0, stream>>>(codebook, ccs);

    patch_sk_kernel<<<dim3(256, 2, 4), 256, 0, stream>>>(image, conv_w, qkv32, h32);
    cpatch_kernel<<<4096, 256, 0, stream>>>(qkv32, h32, conv_b, pos, sf64,
                                            ln1_s, ln1_b, x32, h32);

    for (int i = 0; i < 2; ++i) {
        gemm_kernel<<<dim3(256, 6), 256, 0, stream>>>(h32, 128, qkv_w + (size_t)i*384*128,
                                                      qkv_b + i*384, qkv32, 16384, 384, 128, 0);
        attn_kernel<<<512, 512, 0, stream>>>(qkv32);
        gemm_sk_kernel<<<dim3(256, 2, 2), 256, 0, stream>>>(qkv32, 384,
                                                            out_w + (size_t)i*128*128, 128, 64,
                                                            qkv32 + 128, qkv32 + 256, 384);
        cres_kernel<<<4096, 256, 0, stream>>>(x32, qkv32 + 128, 384, qkv32 + 256, 384,
                                              out_b + i*128, ln2_s + i*128, ln2_b + i*128,
                                              h32, 1);
        gemm_kernel<<<dim3(256, 4), 256, 0, stream>>>(h32, 128, ff1_w + (size_t)i*256*128,
                                                      ff1_b + i*256, qkv32, 16384, 256, 128, 2);
        gemm_sk_kernel<<<dim3(256, 2, 2), 256, 0, stream>>>(qkv32, 256,
                                                            ff2_w + (size_t)i*128*256, 256, 128,
                                                            qkv32 + 4194304, h32, 128);
        cres_kernel<<<4096, 256, 0, stream>>>(x32, qkv32 + 4194304, 128, h32, 128,
                                              ff2_b + i*128, ln1_s + 128, ln1_b + 128,
                                              h32, i == 0 ? 1 : 0);
    }

    vq_dist_kernel<<<dim3(128, 8), 128, 0, stream>>>(x32, codebook, ccs, pbv, pbi);
    vq_merge_kernel<<<512, 256, 0, stream>>>(pbv, pbi, codebook, quant, idxf, counts);
    gf_logits_kernel<<<64, 128, 0, stream>>>(quant, head_w, head_b, gf, logits);
    perp_kernel<<<1, 512, 0, stream>>>(counts, perp);
}

// Round 22
// 449.718 us; speedup vs baseline: 1.1680x; 1.1184x over previous
//
#include <hip/hip_runtime.h>
#include <math.h>

__device__ __forceinline__ void gload16(const float* g, float* l) {
    __builtin_amdgcn_global_load_lds(
        (const __attribute__((address_space(1))) void*)g,
        (__attribute__((address_space(3))) void*)l, 16, 0, 0);
}

// ---------------- stats phase 1 ----------------
__device__ __forceinline__ double wred_add(double v) {
    #pragma unroll
    for (int o = 32; o > 0; o >>= 1) v += __shfl_xor(v, o);
    return v;
}
__device__ __forceinline__ float wred_min(float v) {
    #pragma unroll
    for (int o = 32; o > 0; o >>= 1) v = fminf(v, __shfl_xor(v, o));
    return v;
}
__device__ __forceinline__ float wred_max(float v) {
    #pragma unroll
    for (int o = 32; o > 0; o >>= 1) v = fmaxf(v, __shfl_xor(v, o));
    return v;
}

#define PREC 17

__global__ __launch_bounds__(256) void stats_partial_kernel(const float* __restrict__ img,
                                                            double* __restrict__ part)
{
    int b = blockIdx.x >> 5, blk = blockIdx.x & 31;
    int tid = threadIdx.x;
    const float* r0 = img + (size_t)b * 3 * 65536;
    const float* g0 = r0 + 65536;
    const float* b0 = r0 + 131072;
    int base = blk*2048 + tid*8;
    double s0=0,s1=0,s2=0,q0=0,q1=0,q2=0,l1=0,l2=0,l3=0,l4=0,dark=0;
    float mn0=1e30f,mn1=1e30f,mn2=1e30f, mx0=-1e30f,mx1=-1e30f,mx2=-1e30f;
    #pragma unroll
    for (int u = 0; u < 2; ++u) {
        float4 rv = *(const float4*)&r0[base + u*4];
        float4 gv = *(const float4*)&g0[base + u*4];
        float4 bv = *(const float4*)&b0[base + u*4];
        float rr[4] = {rv.x, rv.y, rv.z, rv.w};
        float gg[4] = {gv.x, gv.y, gv.z, gv.w};
        float bbv[4] = {bv.x, bv.y, bv.z, bv.w};
        #pragma unroll
        for (int e = 0; e < 4; ++e) {
            float r = rr[e], g = gg[e], bl = bbv[e];
            double rd_ = r, gd = g, bd = bl;
            s0 += rd_; q0 += rd_*rd_; mn0 = fminf(mn0, r); mx0 = fmaxf(mx0, r);
            s1 += gd;  q1 += gd*gd;   mn1 = fminf(mn1, g); mx1 = fmaxf(mx1, g);
            s2 += bd;  q2 += bd*bd;   mn2 = fminf(mn2, bl); mx2 = fmaxf(mx2, bl);
            double lum = 0.299*rd_ + 0.587*gd + 0.114*bd;
            double d2 = lum*lum;
            l1 += lum; l2 += d2; l3 += d2*lum; l4 += d2*d2;
            if (lum < 0.2) dark += 1.0;
        }
    }
    double dv[11] = {s0,s1,s2,q0,q1,q2,l1,l2,l3,l4,dark};
    #pragma unroll
    for (int q = 0; q < 11; ++q) dv[q] = wred_add(dv[q]);
    mn0 = wred_min(mn0); mn1 = wred_min(mn1); mn2 = wred_min(mn2);
    mx0 = wred_max(mx0); mx1 = wred_max(mx1); mx2 = wred_max(mx2);
    __shared__ double sd[4][PREC];
    int w = tid >> 6, lane = tid & 63;
    if (lane == 0) {
        #pragma unroll
        for (int q = 0; q < 11; ++q) sd[w][q] = dv[q];
        sd[w][11] = (double)mn0; sd[w][12] = (double)mn1; sd[w][13] = (double)mn2;
        sd[w][14] = (double)mx0; sd[w][15] = (double)mx1; sd[w][16] = (double)mx2;
    }
    __syncthreads();
    if (tid == 0) {
        double out[PREC];
        #pragma unroll
        for (int q = 0; q < PREC; ++q) out[q] = sd[0][q];
        #pragma unroll
        for (int ww = 1; ww < 4; ++ww) {
            #pragma unroll
            for (int q = 0; q < 11; ++q) out[q] += sd[ww][q];
            out[11] = fmin(out[11], sd[ww][11]); out[12] = fmin(out[12], sd[ww][12]);
            out[13] = fmin(out[13], sd[ww][13]);
            out[14] = fmax(out[14], sd[ww][14]); out[15] = fmax(out[15], sd[ww][15]);
            out[16] = fmax(out[16], sd[ww][16]);
        }
        double* p = part + (size_t)(b*32 + blk)*PREC;
        #pragma unroll
        for (int q = 0; q < PREC; ++q) p[q] = out[q];
    }
}

// ---------------- stats phase 2 ----------------
__global__ __launch_bounds__(32) void stats_final_kernel(const double* __restrict__ part,
                                                         double* __restrict__ feats)
{
    int b = blockIdx.x, t = threadIdx.x;
    const double* p = part + (size_t)(b*32 + t)*PREC;
    double v[PREC];
    #pragma unroll
    for (int q = 0; q < PREC; ++q) v[q] = p[q];
    #pragma unroll
    for (int o = 16; o > 0; o >>= 1) {
        #pragma unroll
        for (int q = 0; q < 11; ++q) v[q] += __shfl_xor(v[q], o);
        #pragma unroll
        for (int q = 11; q < 14; ++q) v[q] = fmin(v[q], __shfl_xor(v[q], o));
        #pragma unroll
        for (int q = 14; q < PREC; ++q) v[q] = fmax(v[q], __shfl_xor(v[q], o));
    }
    if (t == 0) {
        const double n = 65536.0;
        double* f = feats + b*15;
        for (int c = 0; c < 3; ++c) {
            double su = v[c], sq = v[3+c];
            f[c]   = su/n;
            f[3+c] = sqrt((sq - su*su/n) / (n - 1.0));
            f[6+c] = v[11+c];
            f[9+c] = v[14+c];
        }
        double m1 = v[6]/n, m2 = v[7]/n, m3 = v[8]/n, m4 = v[9]/n;
        double mu2 = m2 - m1*m1;
        double mu3 = m3 - 3.0*m1*m2 + 2.0*m1*m1*m1;
        double mu4 = m4 - 4.0*m1*m3 + 6.0*m1*m1*m2 - 3.0*m1*m1*m1*m1;
        double sd = sqrt(mu2);
        f[12] = mu3 / (sd*sd*sd + 1e-6);
        f[13] = mu4 / (sd*sd*sd*sd + 1e-6);
        f[14] = v[10] / n;
    }
}

// ---------------- stat MLP ----------------
__global__ __launch_bounds__(128) void sfmlp_kernel(const double* __restrict__ feats,
    const float* __restrict__ w1, const float* __restrict__ b1,
    const float* __restrict__ w2, const float* __restrict__ b2,
    double* __restrict__ sf)
{
    int b = blockIdx.x, t = threadIdx.x;
    __shared__ double fs[15];
    __shared__ double hs[128];
    if (t < 15) fs[t] = feats[b*15 + t];
    __syncthreads();
    double h = (double)b1[t];
    for (int j = 0; j < 15; ++j) h += fs[j] * (double)w1[t*15 + j];
    hs[t] = fmax(h, 0.0);
    __syncthreads();
    double o = (double)b2[t];
    for (int j = 0; j < 128; ++j) o += hs[j] * (double)w2[t*128 + j];
    sf[b*128 + t] = o;
}

__device__ __forceinline__ int swz64(int r, int kq4) {
    return r*64 + (((kq4) ^ (r & 15)) << 2);
}

// ---------------- patch embedding split-K x4 gather-GEMM ----------------
__global__ __launch_bounds__(256) void patch_sk_kernel(const float* __restrict__ img,
    const float* __restrict__ w, float* __restrict__ Pa, float* __restrict__ Pb4)
{
    __shared__ float As[4096];
    __shared__ float Ws[4096];
    int tid = threadIdx.x;
    int tx = tid & 15, ty = tid >> 4;
    int m0 = blockIdx.x * 64, n0 = blockIdx.y * 64;
    int z = blockIdx.z;
    int kbase = z * 192;
    int wv = tid >> 6;
    float acc[4][4] = {};
    for (int k0 = 0; k0 < 192; k0 += 64) {
        #pragma unroll
        for (int call = 0; call < 4; ++call) {
            int s = call*256 + tid;
            int row = s >> 4, kq = (s & 15) ^ (row & 15);
            int m = m0 + row;
            int bb = m >> 8, pat = m & 255;
            int gy = pat >> 4, gx = pat & 15;
            int k = kbase + k0 + kq*4;
            int c = k >> 8, rem = k & 255;
            int py = rem >> 4, px = rem & 15;
            gload16(&img[(size_t)(bb*3 + c)*65536 + (size_t)(gy*16+py)*256 + gx*16 + px],
                    As + (call*256 + wv*64)*4);
            gload16(&w[(size_t)(n0+row)*768 + k], Ws + (call*256 + wv*64)*4);
        }
        __syncthreads();
        #pragma unroll 8
        for (int q = 0; q < 16; ++q) {
            float4 a4[4], w4[4];
            #pragma unroll
            for (int i=0;i<4;++i) a4[i] = *(const float4*)&As[swz64(ty + 16*i, q)];
            #pragma unroll
            for (int j=0;j<4;++j) w4[j] = *(const float4*)&Ws[swz64(tx + 16*j, q)];
            #pragma unroll
            for (int i=0;i<4;++i)
                #pragma unroll
                for (int j=0;j<4;++j) {
                    acc[i][j] = fmaf(a4[i].x, w4[j].x, acc[i][j]);
                    acc[i][j] = fmaf(a4[i].y, w4[j].y, acc[i][j]);
                    acc[i][j] = fmaf(a4[i].z, w4[j].z, acc[i][j]);
                    acc[i][j] = fmaf(a4[i].w, w4[j].w, acc[i][j]);
                }
        }
        __syncthreads();
    }
    float* P = (z < 3) ? (Pa + (size_t)z*2097152) : Pb4;
    #pragma unroll
    for (int i=0;i<4;++i){
        int m = m0 + ty + 16*i;
        #pragma unroll
        for (int j=0;j<4;++j){
            int n = n0 + tx + 16*j;
            P[(size_t)m*128 + n] = acc[i][j];
        }
    }
}

// ---------------- f32 GEMM (global_load_lds staging), epi 0=store+bias, 2=gelu ----------------
__global__ __launch_bounds__(256) void gemm_kernel(const float* __restrict__ A, int lda,
    const float* __restrict__ W, const float* __restrict__ bias,
    float* __restrict__ C, int M, int N, int K, int epi)
{
    __shared__ float As[4096];
    __shared__ float Ws[4096];
    int tid = threadIdx.x;
    int tx = tid & 15, ty = tid >> 4;
    int m0 = blockIdx.x * 64, n0 = blockIdx.y * 64;
    int wv = tid >> 6;
    float acc[4][4] = {};
    for (int k0 = 0; k0 < K; k0 += 64) {
        #pragma unroll
        for (int call = 0; call < 4; ++call) {
            int s = call*256 + tid;
            int row = s >> 4, kq = (s & 15) ^ (row & 15);
            gload16(&A[(size_t)(m0+row)*lda + k0 + kq*4], As + (call*256 + wv*64)*4);
            gload16(&W[(size_t)(n0+row)*K + k0 + kq*4], Ws + (call*256 + wv*64)*4);
        }
        __syncthreads();
        #pragma unroll 8
        for (int q = 0; q < 16; ++q) {
            float4 a4[4], w4[4];
            #pragma unroll
            for (int i=0;i<4;++i) a4[i] = *(const float4*)&As[swz64(ty + 16*i, q)];
            #pragma unroll
            for (int j=0;j<4;++j) w4[j] = *(const float4*)&Ws[swz64(tx + 16*j, q)];
            #pragma unroll
            for (int i=0;i<4;++i)
                #pragma unroll
                for (int j=0;j<4;++j) {
                    acc[i][j] = fmaf(a4[i].x, w4[j].x, acc[i][j]);
                    acc[i][j] = fmaf(a4[i].y, w4[j].y, acc[i][j]);
                    acc[i][j] = fmaf(a4[i].z, w4[j].z, acc[i][j]);
                    acc[i][j] = fmaf(a4[i].w, w4[j].w, acc[i][j]);
                }
        }
        __syncthreads();
    }
    #pragma unroll
    for (int i=0;i<4;++i){
        int m = m0 + ty + 16*i;
        #pragma unroll
        for (int j=0;j<4;++j){
            int n = n0 + tx + 16*j;
            float v = acc[i][j] + bias[n];
            if (epi == 0) {
                C[(size_t)m*N + n] = v;
            } else {
                C[(size_t)m*N + n] = 0.5f*v*(1.0f + erff(v*0.70710678118654752f));
            }
        }
    }
}

// ---------------- split-K f32 GEMM ----------------
__global__ __launch_bounds__(256) void gemm_sk_kernel(const float* __restrict__ A, int lda,
    const float* __restrict__ W, int K, int K2,
    float* __restrict__ P0, float* __restrict__ P1, int ldo)
{
    __shared__ float As[4096];
    __shared__ float Ws[4096];
    int tid = threadIdx.x;
    int tx = tid & 15, ty = tid >> 4;
    int m0 = blockIdx.x * 64, n0 = blockIdx.y * 64;
    int kbase = blockIdx.z * K2;
    int wv = tid >> 6;
    float acc[4][4] = {};
    for (int k0 = 0; k0 < K2; k0 += 64) {
        #pragma unroll
        for (int call = 0; call < 4; ++call) {
            int s = call*256 + tid;
            int row = s >> 4, kq = (s & 15) ^ (row & 15);
            gload16(&A[(size_t)(m0+row)*lda + kbase + k0 + kq*4], As + (call*256 + wv*64)*4);
            gload16(&W[(size_t)(n0+row)*K + kbase + k0 + kq*4], Ws + (call*256 + wv*64)*4);
        }
        __syncthreads();
        #pragma unroll 8
        for (int q = 0; q < 16; ++q) {
            float4 a4[4], w4[4];
            #pragma unroll
            for (int i=0;i<4;++i) a4[i] = *(const float4*)&As[swz64(ty + 16*i, q)];
            #pragma unroll
            for (int j=0;j<4;++j) w4[j] = *(const float4*)&Ws[swz64(tx + 16*j, q)];
            #pragma unroll
            for (int i=0;i<4;++i)
                #pragma unroll
                for (int j=0;j<4;++j) {
                    acc[i][j] = fmaf(a4[i].x, w4[j].x, acc[i][j]);
                    acc[i][j] = fmaf(a4[i].y, w4[j].y, acc[i][j]);
                    acc[i][j] = fmaf(a4[i].z, w4[j].z, acc[i][j]);
                    acc[i][j] = fmaf(a4[i].w, w4[j].w, acc[i][j]);
                }
        }
        __syncthreads();
    }
    float* P = blockIdx.z ? P1 : P0;
    #pragma unroll
    for (int i=0;i<4;++i){
        int m = m0 + ty + 16*i;
        #pragma unroll
        for (int j=0;j<4;++j){
            int n = n0 + tx + 16*j;
            P[(size_t)m*ldo + n] = acc[i][j];
        }
    }
}

// ---------------- combine: x = (((p0+p1)+p2)+p3)+bias+pos+sf ; h = LN(x) ----------------
__global__ __launch_bounds__(256) void cpatch_kernel(const float* __restrict__ pa,
    const float* __restrict__ p3, const float* __restrict__ bias,
    const float* __restrict__ pos, const double* __restrict__ sf,
    const float* __restrict__ ls, const float* __restrict__ lb,
    float* __restrict__ x, float* __restrict__ h)
{
    int tid = threadIdx.x;
    int lane = tid & 63, w = tid >> 6;
    int row = blockIdx.x*4 + w;
    int bb = row >> 8, pat = row & 255;
    int n = lane*2;
    float2 a0 = *(const float2*)&pa[(size_t)row*128 + n];
    float2 a1 = *(const float2*)&pa[2097152 + (size_t)row*128 + n];
    float2 a2 = *(const float2*)&pa[4194304 + (size_t)row*128 + n];
    float2 a3 = *(const float2*)&p3[(size_t)row*128 + n];
    float v0 = ((a0.x + a1.x) + a2.x) + a3.x + bias[n]   + pos[pat*128 + n]   + (float)sf[bb*128 + n];
    float v1 = ((a0.y + a1.y) + a2.y) + a3.y + bias[n+1] + pos[pat*128 + n+1] + (float)sf[bb*128 + n+1];
    *(float2*)&x[(size_t)row*128 + n] = make_float2(v0, v1);
    double v0d = v0, v1d = v1;
    double sum = v0d + v1d, sq = v0d*v0d + v1d*v1d;
    #pragma unroll
    for (int o = 32; o > 0; o >>= 1) { sum += __shfl_xor(sum, o); sq += __shfl_xor(sq, o); }
    double mean = sum * (1.0/128.0);
    double var  = sq  * (1.0/128.0) - mean*mean;
    double inv  = 1.0 / sqrt(var + 1e-5);
    float2 o2;
    o2.x = (float)((v0d - mean)*inv*(double)ls[n]   + (double)lb[n]);
    o2.y = (float)((v1d - mean)*inv*(double)ls[n+1] + (double)lb[n+1]);
    *(float2*)&h[(size_t)row*128 + n] = o2;
}

// ---------------- combine: x += (p0+p1)+bias ; optional h = LN(x) ----------------
__global__ __launch_bounds__(256) void cres_kernel(float* __restrict__ x,
    const float* __restrict__ p0, int ld0, const float* __restrict__ p1, int ld1,
    const float* __restrict__ bias,
    const float* __restrict__ ls, const float* __restrict__ lb,
    float* __restrict__ h, int doLN)
{
    int tid = threadIdx.x;
    int lane = tid & 63, w = tid >> 6;
    int row = blockIdx.x*4 + w;
    int n = lane*2;
    float2 a0 = *(const float2*)&p0[(size_t)row*ld0 + n];
    float2 a1 = *(const float2*)&p1[(size_t)row*ld1 + n];
    float2 xv = *(const float2*)&x[(size_t)row*128 + n];
    float v0 = xv.x + (a0.x + a1.x + bias[n]);
    float v1 = xv.y + (a0.y + a1.y + bias[n+1]);
    *(float2*)&x[(size_t)row*128 + n] = make_float2(v0, v1);
    if (doLN) {
        double v0d = v0, v1d = v1;
        double sum = v0d + v1d, sq = v0d*v0d + v1d*v1d;
        #pragma unroll
        for (int o = 32; o > 0; o >>= 1) { sum += __shfl_xor(sum, o); sq += __shfl_xor(sq, o); }
        double mean = sum * (1.0/128.0);
        double var  = sq  * (1.0/128.0) - mean*mean;
        double inv  = 1.0 / sqrt(var + 1e-5);
        float2 o2;
        o2.x = (float)((v0d - mean)*inv*(double)ls[n]   + (double)lb[n]);
        o2.y = (float)((v1d - mean)*inv*(double)ls[n+1] + (double)lb[n+1]);
        *(float2*)&h[(size_t)row*128 + n] = o2;
    }
}

// ---------------- attention: block (b,h,half), 512 thr, branch-free softmax ----------------
__global__ __launch_bounds__(512, 4) void attn_kernel(float* __restrict__ qkv)
{
    __shared__ float Ks[256*36];
    __shared__ float Vs[256*36];
    int tid = threadIdx.x;
    int b = blockIdx.x >> 3, h = (blockIdx.x >> 1) & 3, half = blockIdx.x & 1;
    {
        int row = tid >> 1, p16 = (tid & 1) * 16;
        size_t rb = (size_t)(b*256 + row) * 384;
        const float* kp = qkv + rb + 128 + h*32 + p16;
        const float* vp = qkv + rb + 256 + h*32 + p16;
        #pragma unroll
        for (int i = 0; i < 4; ++i) {
            *(float4*)&Ks[row*36 + p16 + i*4] = *(const float4*)&kp[i*4];
            *(float4*)&Vs[row*36 + p16 + i*4] = *(const float4*)&vp[i*4];
        }
    }
    int qrow = half*128 + (tid >> 2);
    int ds = (tid >> 1) & 1;
    int ks = tid & 1;
    const float scale = 0.17677669529663687f;
    float q[16];
    const float* qp = qkv + (size_t)(b*256 + qrow)*384 + h*32 + ds*16;
    #pragma unroll
    for (int i = 0; i < 16; ++i) q[i] = qp[i] * scale;
    __syncthreads();
    float o[16];
    #pragma unroll
    for (int i = 0; i < 16; ++i) o[i] = 0.f;
    float l = 0.f;
    for (int it = 0; it < 128; ++it) {
        int j = it*2 + ks;
        const float* kr = &Ks[j*36 + ds*16];
        float s = 0.f;
        #pragma unroll
        for (int i = 0; i < 16; ++i) s = fmaf(q[i], kr[i], s);
        s += __shfl_xor(s, 2);
        float e = __expf(s);
        l += e;
        const float* vr = &Vs[j*36 + ds*16];
        #pragma unroll
        for (int i = 0; i < 16; ++i) o[i] = fmaf(e, vr[i], o[i]);
    }
    l += __shfl_xor(l, 1);
    #pragma unroll
    for (int i = 0; i < 16; ++i) o[i] += __shfl_xor(o[i], 1);
    if (ks == 0) {
        float inv = 1.0f / l;
        float* op = qkv + (size_t)(b*256 + qrow)*384 + h*32 + ds*16;
        #pragma unroll
        for (int i = 0; i < 16; ++i) op[i] = o[i] * inv;
    }
}

// ---------------- VQ: cc precompute ----------------
__global__ __launch_bounds__(256) void cc_kernel(const float* __restrict__ cb,
                                                 float* __restrict__ ccs)
{
    int c = blockIdx.x*256 + threadIdx.x;
    const float* p = cb + (size_t)c*128;
    float r[8];
    #pragma unroll
    for (int j = 0; j < 8; ++j) { float v = p[j]; r[j] = v*v; }
    for (int i = 8; i < 128; i += 8)
        #pragma unroll
        for (int j = 0; j < 8; ++j) { float v = p[i+j]; r[j] += v*v; }
    ccs[c] = ((r[0]+r[1]) + (r[2]+r[3])) + ((r[4]+r[5]) + (r[6]+r[7]));
}

#define ZC(k) (((k)&3)==0 ? z[(k)>>2].x : ((k)&3)==1 ? z[(k)>>2].y : ((k)&3)==2 ? z[(k)>>2].z : z[(k)>>2].w)

// ---------------- VQ distance pass ----------------
__global__ __launch_bounds__(128) void vq_dist_kernel(const float* __restrict__ x,
    const float* __restrict__ cb, const float* __restrict__ ccs,
    float* __restrict__ pbv, int* __restrict__ pbi)
{
    __shared__ float Cs[8192];
    __shared__ float ccl[64];
    int tid = threadIdx.x;
    int m = blockIdx.x*128 + tid;
    int split = blockIdx.y;
    int cbase = split*64;
    const float4* cbp = (const float4*)(cb + (size_t)cbase*128);
    for (int e = tid; e < 2048; e += 128) ((float4*)Cs)[e] = cbp[e];
    if (tid < 64) ccl[tid] = ccs[cbase + tid];
    float4 z[32];
    const float4* zp = (const float4*)(x + (size_t)m*128);
    #pragma unroll
    for (int i = 0; i < 32; ++i) z[i] = zp[i];
    float r[8];
    #pragma unroll
    for (int j = 0; j < 8; ++j) { float v = ZC(j); r[j] = v*v; }
    #pragma unroll
    for (int i = 8; i < 128; i += 8)
        #pragma unroll
        for (int j = 0; j < 8; ++j) { float v = ZC(i+j); r[j] += v*v; }
    float zz = ((r[0]+r[1]) + (r[2]+r[3])) + ((r[4]+r[5]) + (r[6]+r[7]));
    __syncthreads();
    float bestv = INFINITY;
    int   besti = 0;
    for (int g = 0; g < 16; ++g) {
        const float* c0 = &Cs[(g*4+0)*128];
        const float* c1 = &Cs[(g*4+1)*128];
        const float* c2 = &Cs[(g*4+2)*128];
        const float* c3 = &Cs[(g*4+3)*128];
        float a0 = 0.f, a1 = 0.f, a2 = 0.f, a3 = 0.f;
        #pragma unroll
        for (int q = 0; q < 32; ++q) {
            float4 v0 = *(const float4*)&c0[q*4];
            float4 v1 = *(const float4*)&c1[q*4];
            float4 v2 = *(const float4*)&c2[q*4];
            float4 v3 = *(const float4*)&c3[q*4];
            float4 zq = z[q];
            a0 = fmaf(zq.x, v0.x, a0); a0 = fmaf(zq.y, v0.y, a0);
            a0 = fmaf(zq.z, v0.z, a0); a0 = fmaf(zq.w, v0.w, a0);
            a1 = fmaf(zq.x, v1.x, a1); a1 = fmaf(zq.y, v1.y, a1);
            a1 = fmaf(zq.z, v1.z, a1); a1 = fmaf(zq.w, v1.w, a1);
            a2 = fmaf(zq.x, v2.x, a2); a2 = fmaf(zq.y, v2.y, a2);
            a2 = fmaf(zq.z, v2.z, a2); a2 = fmaf(zq.w, v2.w, a2);
            a3 = fmaf(zq.x, v3.x, a3); a3 = fmaf(zq.y, v3.y, a3);
            a3 = fmaf(zq.z, v3.z, a3); a3 = fmaf(zq.w, v3.w, a3);
        }
        int code = cbase + g*4;
        float t1, d;
        t1 = zz + ccl[g*4+0]; d = t1 - 2.0f*a0; if (d < bestv) { bestv = d; besti = code;   }
        t1 = zz + ccl[g*4+1]; d = t1 - 2.0f*a1; if (d < bestv) { bestv = d; besti = code+1; }
        t1 = zz + ccl[g*4+2]; d = t1 - 2.0f*a2; if (d < bestv) { bestv = d; besti = code+2; }
        t1 = zz + ccl[g*4+3]; d = t1 - 2.0f*a3; if (d < bestv) { bestv = d; besti = code+3; }
    }
    pbv[(size_t)split*16384 + m] = bestv;
    pbi[(size_t)split*16384 + m] = besti;
}

// ---------------- VQ merge: 512 blocks x 32 rows, NO global atomics ----------------
__global__ __launch_bounds__(256) void vq_merge_kernel(const float* __restrict__ pbv,
    const int* __restrict__ pbi, const float* __restrict__ cb,
    float* __restrict__ quant, float* __restrict__ idxf)
{
    __shared__ int fidx[32];
    int tid = threadIdx.x;
    int m0 = blockIdx.x*32;
    if (tid < 32) {
        int m = m0 + tid;
        float v = pbv[m]; int gi = pbi[m];
        #pragma unroll
        for (int s = 1; s < 8; ++s) {
            float vv = pbv[(size_t)s*16384 + m]; int ii = pbi[(size_t)s*16384 + m];
            if (vv < v) { v = vv; gi = ii; }   // ascending splits: ties keep lower index
        }
        fidx[tid] = gi;
        idxf[m] = (float)gi;
    }
    __syncthreads();
    #pragma unroll
    for (int e0 = 0; e0 < 4; ++e0) {
        int e = e0*256 + tid;
        int rr = e >> 5, k4 = e & 31;
        ((float4*)&quant[(size_t)(m0+rr)*128])[k4] = ((const float4*)&cb[(size_t)fidx[rr]*128])[k4];
    }
}

// ---------------- gf + logits ----------------
__global__ __launch_bounds__(128) void gf_logits_kernel(const float* __restrict__ quant,
    const float* __restrict__ head_w, const float* __restrict__ head_b,
    float* __restrict__ gf, float* __restrict__ logits)
{
    int b = blockIdx.x, d = threadIdx.x;
    double s = 0.0;
    for (int n = 0; n < 256; ++n) s += (double)quant[(size_t)(b*256+n)*128 + d];
    double g = s * (1.0/256.0);
    gf[b*128 + d] = (float)g;
    __shared__ double gs[128];
    gs[d] = g;
    __syncthreads();
    if (d < 8) {
        double l = (double)head_b[d];
        for (int k = 0; k < 128; ++k) l += gs[k] * (double)head_w[d*128 + k];
        logits[b*8 + d] = (float)l;
    }
}

// ---------------- perplexity via LDS histogram (16 wave-private copies) ----------------
__global__ __launch_bounds__(1024) void perp_kernel(const float* __restrict__ idxf,
                                                    float* __restrict__ out)
{
    __shared__ int hist[16][512];     // 32 KB
    __shared__ double sh[1024];
    int t = threadIdx.x;
    int wv = t >> 6;                  // 16 waves
    for (int i = t; i < 16*512; i += 1024) ((int*)hist)[i] = 0;
    __syncthreads();
    for (int i = t; i < 16384; i += 1024) {
        int gi = (int)idxf[i];
        atomicAdd(&hist[wv][gi], 1);
    }
    __syncthreads();
    double acc = 0.0;
    if (t < 512) {
        int s = 0;
        #pragma unroll
        for (int w2 = 0; w2 < 16; ++w2) s += hist[w2][t];
        double p = (double)s * (1.0/16384.0);
        acc = p * log(p + 1e-10);
    }
    sh[t] = acc;
    __syncthreads();
    for (int s2 = 512; s2 > 0; s2 >>= 1) { if (t < s2) sh[t] += sh[t+s2]; __syncthreads(); }
    if (t == 0) out[0] = (float)exp(-sh[0]);
}

extern "C" void kernel_launch(void* const* d_in, const int* in_sizes, int n_in,
                              void* d_out, int out_size, void* d_ws, size_t ws_size,
                              hipStream_t stream)
{
    const float* image   = (const float*)d_in[0];
    const float* conv_w  = (const float*)d_in[1];
    const float* conv_b  = (const float*)d_in[2];
    const float* stat_w1 = (const float*)d_in[3];
    const float* stat_b1 = (const float*)d_in[4];
    const float* stat_w2 = (const float*)d_in[5];
    const float* stat_b2 = (const float*)d_in[6];
    const float* pos     = (const float*)d_in[7];
    const float* ln1_s   = (const float*)d_in[8];
    const float* ln1_b   = (const float*)d_in[9];
    const float* qkv_w   = (const float*)d_in[10];
    const float* qkv_b   = (const float*)d_in[11];
    const float* out_w   = (const float*)d_in[12];
    const float* out_b   = (const float*)d_in[13];
    const float* ln2_s   = (const float*)d_in[14];
    const float* ln2_b   = (const float*)d_in[15];
    const float* ff1_w   = (const float*)d_in[16];
    const float* ff1_b   = (const float*)d_in[17];
    const float* ff2_w   = (const float*)d_in[18];
    const float* ff2_b   = (const float*)d_in[19];
    const float* codebook= (const float*)d_in[20];
    const float* head_w  = (const float*)d_in[21];
    const float* head_b  = (const float*)d_in[22];

    char* wsb = (char*)d_ws;
    float*  x32   = (float*) (wsb);                            //  8,388,608 B
    float*  h32   = (float*) (wsb + 8388608);                  //  8,388,608 B
    float*  qkv32 = (float*) (wsb + 16777216);                 // 25,165,824 B
    double* sf64  = (double*)(wsb + 41943040);                 //     65,536 B
    double* feats = (double*)(wsb + 42008576);                 //      7,680 B
    double* part  = (double*)(wsb + 42018304);                 //    278,528 B
    float*  pbv   = (float*) (wsb + 42296832);                 //    524,288 B
    int*    pbi   = (int*)   (wsb + 42821120);                 //    524,288 B
    float*  ccs   = (float*) (wsb + 43345408);                 //      2,048 B

    float* outf   = (float*)d_out;
    float* quant  = outf;
    float* idxf   = quant + 2097152;
    float* logits = idxf + 16384;
    float* gf     = logits + 512;
    float* perp   = gf + 8192;

    stats_partial_kernel<<<2048, 256, 0, stream>>>(image, part);
    stats_final_kernel<<<64, 32, 0, stream>>>(part, feats);
    sfmlp_kernel<<<64, 128, 0, stream>>>(feats, stat_w1, stat_b1, stat_w2, stat_b2, sf64);
    cc_kernel<<<2, 256, 0, stream>>>(codebook, ccs);

    patch_sk_kernel<<<dim3(256, 2, 4), 256, 0, stream>>>(image, conv_w, qkv32, h32);
    cpatch_kernel<<<4096, 256, 0, stream>>>(qkv32, h32, conv_b, pos, sf64,
                                            ln1_s, ln1_b, x32, h32);

    for (int i = 0; i < 2; ++i) {
        gemm_kernel<<<dim3(256, 6), 256, 0, stream>>>(h32, 128, qkv_w + (size_t)i*384*128,
                                                      qkv_b + i*384, qkv32, 16384, 384, 128, 0);
        attn_kernel<<<512, 512, 0, stream>>>(qkv32);
        gemm_sk_kernel<<<dim3(256, 2, 2), 256, 0, stream>>>(qkv32, 384,
                                                            out_w + (size_t)i*128*128, 128, 64,
                                                            qkv32 + 128, qkv32 + 256, 384);
        cres_kernel<<<4096, 256, 0, stream>>>(x32, qkv32 + 128, 384, qkv32 + 256, 384,
                                              out_b + i*128, ln2_s + i*128, ln2_b + i*128,
                                              h32, 1);
        gemm_kernel<<<dim3(256, 4), 256, 0, stream>>>(h32, 128, ff1_w + (size_t)i*256*128,
                                                      ff1_b + i*256, qkv32, 16384, 256, 128, 2);
        gemm_sk_kernel<<<dim3(256, 2, 2), 256, 0, stream>>>(qkv32, 256,
                                                            ff2_w + (size_t)i*128*256, 256, 128,
                                                            qkv32 + 4194304, h32, 128);
        cres_kernel<<<4096, 256, 0, stream>>>(x32, qkv32 + 4194304, 128, h32, 128,
                                              ff2_b + i*128, ln1_s + 128, ln1_b + 128,
                                              h32, i == 0 ? 1 : 0);
    }

    vq_dist_kernel<<<dim3(128, 8), 128, 0, stream>>>(x32, codebook, ccs, pbv, pbi);
    vq_merge_kernel<<<512, 256, 0, stream>>>(pbv, pbi, codebook, quant, idxf);
    gf_logits_kernel<<<64, 128, 0, stream>>>(quant, head_w, head_b, gf, logits);
    perp_kernel<<<1, 1024, 0, stream>>>(idxf, perp);
}